// Round 7
// baseline (1344.762 us; speedup 1.0000x reference)
//
#include <hip/hip_runtime.h>
#include <hip/hip_fp16.h>
#include <math.h>
#include <stdint.h>

// =================== problem constants ===================
constexpr int Bb = 4;
constexpr int Nn = 8192;
constexpr int Ee = 65536;
constexpr int BN = Bb * Nn;   // 32768 nodes
constexpr int BE = Bb * Ee;   // 262144 edges
constexpr int NW = 374;       // radial weight columns
constexpr int NWU = NW * 16;  // u32 (f16x2) elements in the table

// w3j tie-break signs — VERIFIED round 1 (absmax 0.0)
#define S111 (+1.0f)
#define S122 (-1.0f)
#define S221 (-1.0f)
#define S222 (-1.0f)

#define SQ3f   1.7320508075688772f
#define SQ15f  3.872983346207417f
#define HSQ5f  1.118033988749895f
#define HSQ15f 1.9364916731037085f
#define RS10f  0.31622776601683794f
#define RS3f   0.5773502691896258f
#define RS32f  0.17677669529663687f
#define K1f    0.5773502691896258f
#define K2f    0.4472135954999579f
#define K6f    0.40824829046386296f
#define A0f    0.24253562503633297f
#define A1f    0.3612106650782119f
#define A2f    0.4803844614152614f
#define A3f    0.4564354645876384f
#define A112f  0.31622776601683794f
#define B112f  0.3651483716701107f
#define C112f  0.18257418583505536f
#define G122f  0.18257418583505536f
#define H122f  0.31622776601683794f
#define F122f  0.3651483716701107f
#define P222f  0.11952286093343936f
#define SP222f 0.20701966780270626f

#define PS1  (A0f*RS32f)
#define PS2  (A1f*RS32f*K1f)
#define PS3  (A3f*RS32f*K2f)
#define PS4  (A1f*RS32f*K1f)
#define PS5  (A0f*RS32f*K1f)
#define PS6  (A2f*RS32f*K6f*S111)
#define PS7  (A3f*RS32f)
#define PS8  (A1f*RS32f)
#define PS9  (A2f*RS32f*K1f)
#define PS10 (A1f*RS32f*K6f*S111)
#define PS11 (A2f*RS32f)
#define PS12 (A3f*RS32f*S122)
#define PS13 (A3f*RS32f*K2f)
#define PS14 (A1f*RS32f)
#define PS15 (A0f*RS32f*K2f)
#define PS16 (A2f*RS32f*S221)
#define PS17 (A3f*RS32f*S222)

typedef _Float16 h2v __attribute__((ext_vector_type(2)));   // fdot2 operand type
typedef __fp16   p2v __attribute__((ext_vector_type(2)));   // cvt_pkrtz result type
union H2U { uint32_t u; h2v h; p2v p; };

__device__ __forceinline__ float sigm(float z) { return 1.f / (1.f + __expf(-z)); }

// dot over 32 radial-hidden units; LDS broadcast reads; 2 accumulators halve the dep chain
__device__ __forceinline__ float wdoth(const uint32_t* sW,
                                       const uint32_t hid2[16], int col) {
  float a0 = 0.f, a1 = 0.f;
  const uint32_t* p = sW + col * 16;
#pragma unroll
  for (int q = 0; q < 16; q += 2) {
    H2U x0; x0.u = hid2[q];     H2U y0; y0.u = p[q];
    H2U x1; x1.u = hid2[q + 1]; H2U y1; y1.u = p[q + 1];
#if defined(__has_builtin) && __has_builtin(__builtin_amdgcn_fdot2)
    a0 = __builtin_amdgcn_fdot2(x0.h, y0.h, a0, false);
    a1 = __builtin_amdgcn_fdot2(x1.h, y1.h, a1, false);
#else
    a0 = fmaf((float)x0.h[0], (float)y0.h[0], a0);
    a0 = fmaf((float)x0.h[1], (float)y0.h[1], a0);
    a1 = fmaf((float)x1.h[0], (float)y1.h[0], a1);
    a1 = fmaf((float)x1.h[1], (float)y1.h[1], a1);
#endif
  }
  return a0 + a1;
}

// =================== transpose+convert rad_w2 -> f16 packed [L][374][16] ===================
__global__ void k_tr(const float* __restrict__ R2all, uint32_t* __restrict__ T) {
  int t = blockIdx.x * blockDim.x + threadIdx.x;
  if (t >= 2 * NW) return;
  int l = t / NW, c = t - l * NW;
  const float* src = R2all + (size_t)l * 32 * NW + c;
  uint32_t* dst = T + (size_t)t * 16;
#pragma unroll
  for (int p = 0; p < 16; ++p) {
    H2U u;
    u.p = __builtin_amdgcn_cvt_pkrtz(src[(size_t)(2 * p) * NW], src[(size_t)(2 * p + 1) * NW]);
    dst[p] = u.u;
  }
}

// =================== encoder ===================
__global__ void k_enc(const float* __restrict__ xn, const float* __restrict__ mask_n,
                      const float* __restrict__ ew0, const float* __restrict__ eb0,
                      const float* __restrict__ ew1e, const float* __restrict__ ew2e,
                      float* __restrict__ h) {
  int t = blockIdx.x * blockDim.x + threadIdx.x;
  if (t >= BN) return;
  const float* x9 = xn + (size_t)t * 9;
  float U00 = x9[0], U01 = x9[1], U02 = x9[2];
  float U10 = x9[3], U11 = x9[4], U12 = x9[5];
  float U20 = x9[6], U21 = x9[7], U22 = x9[8];
  float tr = U00 + U11 + U22;
  float a[5];
  a[0] = (2.f * U22 - U00 - U11) * 0.4082482904638630f;
  a[1] = (U00 - U11) * 0.7071067811865476f;
  a[2] = 0.7071067811865476f * (U01 + U10);
  a[3] = 0.7071067811865476f * (U02 + U20);
  a[4] = 0.7071067811865476f * (U12 + U21);
  float om[3];
  om[0] = 0.5f * (U12 - U21);
  om[1] = 0.5f * (U20 - U02);
  om[2] = 0.5f * (U01 - U10);
  float mk = mask_n[t];
  float o[48];
#pragma unroll
  for (int j = 0; j < 10; ++j) o[j] = (tr * ew0[j] + eb0[j]) * mk;
#pragma unroll
  for (int j = 10; j < 19; ++j) o[j] = 0.f;
#pragma unroll
  for (int w = 0; w < 3; ++w)
#pragma unroll
    for (int mm = 0; mm < 3; ++mm) o[19 + w * 3 + mm] = om[mm] * ew1e[w] * mk;
#pragma unroll
  for (int w = 0; w < 4; ++w)
#pragma unroll
    for (int mm = 0; mm < 5; ++mm) o[28 + w * 5 + mm] = a[mm] * ew2e[w] * mk;
  float4* hp = (float4*)(h + (size_t)t * 48);
#pragma unroll
  for (int q = 0; q < 12; ++q) hp[q] = ((float4*)o)[q];
}

// =================== per-channel linear (lin_hid) ===================
__device__ __forceinline__ void lin48(const float h[48], const float* __restrict__ w0,
                                      const float* __restrict__ b0, const float* __restrict__ w1o,
                                      const float* __restrict__ w1e, const float* __restrict__ w2e,
                                      float o[48]) {
#pragma unroll
  for (int j = 0; j < 10; ++j) {
    float s = 0.f;
#pragma unroll
    for (int u = 0; u < 10; ++u) s = fmaf(h[u], w0[u * 10 + j], s);
    o[j] = s * RS10f + b0[j];
  }
#pragma unroll
  for (int w = 0; w < 3; ++w) {
#pragma unroll
    for (int m = 0; m < 3; ++m) {
      float s1 = 0.f, s2 = 0.f;
#pragma unroll
      for (int u = 0; u < 3; ++u) {
        s1 = fmaf(h[10 + u * 3 + m], w1o[u * 3 + w], s1);
        s2 = fmaf(h[19 + u * 3 + m], w1e[u * 3 + w], s2);
      }
      o[10 + w * 3 + m] = s1 * RS3f;
      o[19 + w * 3 + m] = s2 * RS3f;
    }
  }
#pragma unroll
  for (int w = 0; w < 4; ++w) {
#pragma unroll
    for (int m = 0; m < 5; ++m) {
      float s = 0.f;
#pragma unroll
      for (int u = 0; u < 4; ++u) s = fmaf(h[28 + u * 5 + m], w2e[u * 4 + w], s);
      o[28 + w * 5 + m] = s * 0.5f;
    }
  }
}

__global__ void k_lin(const float* __restrict__ hin, const float* __restrict__ w0,
                      const float* __restrict__ b0, const float* __restrict__ w1o,
                      const float* __restrict__ w1e, const float* __restrict__ w2e,
                      float* __restrict__ hout) {
  int t = blockIdx.x * blockDim.x + threadIdx.x;
  if (t >= BN) return;
  float h[48], o[48];
  const float4* hp = (const float4*)(hin + (size_t)t * 48);
#pragma unroll
  for (int q = 0; q < 12; ++q) ((float4*)h)[q] = hp[q];
  lin48(h, w0, b0, w1o, w1e, w2e, o);
  float4* op = (float4*)(hout + (size_t)t * 48);
#pragma unroll
  for (int q = 0; q < 12; ++q) op[q] = ((float4*)o)[q];
}

// =================== CSR build (e_dst is constant across layers) ===================
__global__ void k_count(const int* __restrict__ edst, int* __restrict__ deg) {
  int t = blockIdx.x * blockDim.x + threadIdx.x;
  if (t >= BE) return;
  int b = t >> 16;
  atomicAdd(&deg[edst[t] + (b << 13)], 1);
}

__global__ void k_scan_block(const int* __restrict__ deg, int* __restrict__ off,
                             int* __restrict__ bsum) {
  __shared__ int sh[256];
  int i = threadIdx.x, g = blockIdx.x * 256 + i;
  int v = deg[g];
  sh[i] = v;
  __syncthreads();
  for (int d = 1; d < 256; d <<= 1) {
    int tv = (i >= d) ? sh[i - d] : 0;
    __syncthreads();
    sh[i] += tv;
    __syncthreads();
  }
  off[g] = sh[i] - v;  // exclusive within block
  if (i == 255) bsum[blockIdx.x] = sh[i];
}

__global__ void k_scan_bsum(int* __restrict__ bsum, int* __restrict__ boff) {
  __shared__ int sh[128];
  int i = threadIdx.x;
  int v = bsum[i];
  sh[i] = v;
  __syncthreads();
  for (int d = 1; d < 128; d <<= 1) {
    int tv = (i >= d) ? sh[i - d] : 0;
    __syncthreads();
    sh[i] += tv;
    __syncthreads();
  }
  boff[i] = sh[i] - v;  // exclusive
}

__global__ void k_scan_add(const int* __restrict__ boff, int* __restrict__ off,
                           int* __restrict__ cursor) {
  int g = blockIdx.x * 256 + threadIdx.x;
  int v = off[g] + boff[blockIdx.x];
  off[g] = v;
  cursor[g] = v;
  if (g == 0) off[BN] = BE;
}

// epos[t] = CSR slot of edge t -> k_msg stores in CSR order, k_agg reads contiguous
__global__ void k_fill(const int* __restrict__ edst, int* __restrict__ cursor,
                       int* __restrict__ epos) {
  int t = blockIdx.x * blockDim.x + threadIdx.x;
  if (t >= BE) return;
  int b = t >> 16;
  int d = edst[t] + (b << 13);
  int pos = atomicAdd(&cursor[d], 1);
  epos[t] = pos;
}

// ===== shared prologue for the message kernels =====
#define MSG_PROLOGUE                                                            \
  __shared__ uint32_t sW[NWU];                                                  \
  int tid = threadIdx.x;                                                        \
  _Pragma("unroll")                                                             \
  for (int i = 0; i < (NWU + 255) / 256; ++i) {                                 \
    int idx = tid + i * 256;                                                    \
    if (idx < NWU) sW[idx] = W16[idx];                                          \
  }                                                                             \
  __syncthreads();                                                              \
  int t = blockIdx.x * blockDim.x + tid;                                        \
  if (t >= BE) return;                                                          \
  int b = t >> 16;                                                              \
  int srow = esrc[t] + (b << 13);                                               \
  float mke = mask_e[t];                                                        \
  float ey = e_attr2[2 * t] * mke;                                              \
  float ez = e_attr2[2 * t + 1] * mke;                                          \
  float rn = sqrtf(ey * ey + ez * ez) + 1e-8f;                                  \
  float yy = ey / rn, zz = ez / rn;                                             \
  const float Z1[3] = {0.f, SQ3f * yy, SQ3f * zz};                              \
  const float Z2[5] = {0.f, SQ15f * yy * zz, HSQ5f * (2.f * zz * zz - yy * yy), \
                       0.f, -HSQ15f * yy * yy};                                 \
  uint32_t hid2[16];                                                            \
  _Pragma("unroll")                                                             \
  for (int q = 0; q < 16; ++q) {                                                \
    float z0 = rn * rw1[2 * q];                                                 \
    float z1 = rn * rw1[2 * q + 1];                                             \
    H2U u;                                                                      \
    u.p = __builtin_amdgcn_cvt_pkrtz(z0 * sigm(z0), z1 * sigm(z1));             \
    hid2[q] = u.u;                                                              \
  }                                                                             \
  float xs[48];                                                                 \
  {                                                                             \
    const float4* hp = (const float4*)(HIN + (size_t)srow * 48);                \
    _Pragma("unroll")                                                           \
    for (int q = 0; q < 12; ++q) ((float4*)xs)[q] = hp[q];                      \
  }

// =================== message kernel A: outputs l0 (o0..9) + l1o (o10..18) ===================
__global__ __launch_bounds__(256, 4) void k_msgA(
    const float* __restrict__ HIN, const float* __restrict__ e_attr2,
    const float* __restrict__ mask_e, const float* __restrict__ rw1,
    const uint32_t* __restrict__ W16, const int* __restrict__ esrc,
    const int* __restrict__ epos, float* __restrict__ MSG) {
  MSG_PROLOGUE
  float o[19];
#pragma unroll
  for (int j = 0; j < 19; ++j) o[j] = 0.f;

  // ---- P1 (l0 x Y0 -> l0), wa=0 ----
#pragma unroll
  for (int u = 0; u < 10; ++u) {
    float xu = PS1 * xs[u];
#pragma unroll
    for (int w = 0; w < 10; ++w) o[w] = fmaf(wdoth(sW, hid2, u * 10 + w), xu, o[w]);
  }
  // ---- P2 (l0 x Y1 -> l1o), wa=100 (t0 = xu*Z1[0] = 0) ----
#pragma unroll
  for (int u = 0; u < 10; ++u) {
    float xu = PS2 * xs[u];
    float t1 = xu * Z1[1], t2 = xu * Z1[2];
#pragma unroll
    for (int w = 0; w < 3; ++w) {
      float wv = wdoth(sW, hid2, 100 + u * 3 + w);
      o[10 + w * 3 + 1] = fmaf(wv, t1, o[10 + w * 3 + 1]);
      o[10 + w * 3 + 2] = fmaf(wv, t2, o[10 + w * 3 + 2]);
    }
  }
  // ---- P4 (l1o x Y0 -> l1o), wa=170 ----
#pragma unroll
  for (int u = 0; u < 3; ++u) {
    float t0 = PS4 * xs[10 + u * 3 + 0], t1 = PS4 * xs[10 + u * 3 + 1], t2 = PS4 * xs[10 + u * 3 + 2];
#pragma unroll
    for (int w = 0; w < 3; ++w) {
      float wv = wdoth(sW, hid2, 170 + u * 3 + w);
      o[10 + w * 3 + 0] = fmaf(wv, t0, o[10 + w * 3 + 0]);
      o[10 + w * 3 + 1] = fmaf(wv, t1, o[10 + w * 3 + 1]);
      o[10 + w * 3 + 2] = fmaf(wv, t2, o[10 + w * 3 + 2]);
    }
  }
  // ---- P5 (l1o x Y1 -> l0), wa=179 ----
#pragma unroll
  for (int u = 0; u < 3; ++u) {
    float s = PS5 * (xs[10 + u * 3 + 1] * Z1[1] + xs[10 + u * 3 + 2] * Z1[2]);
#pragma unroll
    for (int w = 0; w < 10; ++w) o[w] = fmaf(wdoth(sW, hid2, 179 + u * 10 + w), s, o[w]);
  }
  // ---- P8 (l1o x Y2 -> l1o), C121, wa=230 (Z2[0]=Z2[3]=0) ----
#pragma unroll
  for (int u = 0; u < 3; ++u) {
    float X0 = xs[10 + u * 3 + 0], X1 = xs[10 + u * 3 + 1], X2 = xs[10 + u * 3 + 2];
    float t0 = PS8 * (A112f * X0 * Z2[4] - C112f * X0 * Z2[2]);
    float t1 = PS8 * (A112f * (X2 * Z2[1] - X1 * Z2[4]) - C112f * X1 * Z2[2]);
    float t2 = PS8 * (A112f * X1 * Z2[1] + B112f * X2 * Z2[2]);
#pragma unroll
    for (int w = 0; w < 3; ++w) {
      float wv = wdoth(sW, hid2, 230 + u * 3 + w);
      o[10 + w * 3 + 0] = fmaf(wv, t0, o[10 + w * 3 + 0]);
      o[10 + w * 3 + 1] = fmaf(wv, t1, o[10 + w * 3 + 1]);
      o[10 + w * 3 + 2] = fmaf(wv, t2, o[10 + w * 3 + 2]);
    }
  }
  // ---- P10 (l1e x Y1 -> l1o), eps, wa=248 (Z1[0]=0) ----
#pragma unroll
  for (int u = 0; u < 3; ++u) {
    float X0 = xs[19 + u * 3 + 0], X1 = xs[19 + u * 3 + 1], X2 = xs[19 + u * 3 + 2];
    float c0 = PS10 * (X1 * Z1[2] - X2 * Z1[1]);
    float c1 = PS10 * (-X0 * Z1[2]);
    float c2 = PS10 * (X0 * Z1[1]);
#pragma unroll
    for (int w = 0; w < 3; ++w) {
      float wv = wdoth(sW, hid2, 248 + u * 3 + w);
      o[10 + w * 3 + 0] = fmaf(wv, c0, o[10 + w * 3 + 0]);
      o[10 + w * 3 + 1] = fmaf(wv, c1, o[10 + w * 3 + 1]);
      o[10 + w * 3 + 2] = fmaf(wv, c2, o[10 + w * 3 + 2]);
    }
  }
  // ---- P14 (l2 x Y1 -> l1o), C211, wa=294 (Z1[0]=0) ----
#pragma unroll
  for (int u = 0; u < 4; ++u) {
    float Xa0 = xs[28 + u * 5 + 0], Xa1 = xs[28 + u * 5 + 1], Xa2 = xs[28 + u * 5 + 2];
    float Xa3 = xs[28 + u * 5 + 3], Xa4 = xs[28 + u * 5 + 4];
    float t0 = PS14 * (A112f * (Z1[1] * Xa0 + Z1[2] * Xa3));
    float t1 = PS14 * (A112f * (Z1[2] * Xa1 - Z1[1] * Xa4) - C112f * Z1[1] * Xa2);
    float t2 = PS14 * (A112f * Z1[1] * Xa1 + B112f * Z1[2] * Xa2);
#pragma unroll
    for (int w = 0; w < 3; ++w) {
      float wv = wdoth(sW, hid2, 294 + u * 3 + w);
      o[10 + w * 3 + 0] = fmaf(wv, t0, o[10 + w * 3 + 0]);
      o[10 + w * 3 + 1] = fmaf(wv, t1, o[10 + w * 3 + 1]);
      o[10 + w * 3 + 2] = fmaf(wv, t2, o[10 + w * 3 + 2]);
    }
  }
  // ---- P15 (l2 x Y2 -> l0), wa=306 (Z2[0]=Z2[3]=0) ----
#pragma unroll
  for (int u = 0; u < 4; ++u) {
    float s = PS15 * (xs[28 + u * 5 + 1] * Z2[1] + xs[28 + u * 5 + 2] * Z2[2] + xs[28 + u * 5 + 4] * Z2[4]);
#pragma unroll
    for (int w = 0; w < 10; ++w) o[w] = fmaf(wdoth(sW, hid2, 306 + u * 10 + w), s, o[w]);
  }

  // ---- store o[0:19] into CSR-ordered MSG row ----
  float* mp = MSG + (size_t)epos[t] * 48;
#pragma unroll
  for (int q = 0; q < 4; ++q) ((float4*)mp)[q] = ((float4*)o)[q];
  mp[16] = o[16]; mp[17] = o[17]; mp[18] = o[18];
}

// =================== message kernel B: outputs l1e (o19..27) + l2 (o28..47) ===================
__global__ __launch_bounds__(256, 4) void k_msgB(
    const float* __restrict__ HIN, const float* __restrict__ e_attr2,
    const float* __restrict__ mask_e, const float* __restrict__ rw1,
    const uint32_t* __restrict__ W16, const int* __restrict__ esrc,
    const int* __restrict__ epos, float* __restrict__ MSG) {
  MSG_PROLOGUE
  float oe[9];   // l1e -> global o[19..27]
  float o2[20];  // l2  -> global o[28..47]
#pragma unroll
  for (int j = 0; j < 9; ++j) oe[j] = 0.f;
#pragma unroll
  for (int j = 0; j < 20; ++j) o2[j] = 0.f;

  // ---- P3 (l0 x Y2 -> l2), wa=130 (Z2[0]=Z2[3]=0) ----
#pragma unroll
  for (int u = 0; u < 10; ++u) {
    float xu = PS3 * xs[u];
    float m1 = xu * Z2[1], m2 = xu * Z2[2], m4 = xu * Z2[4];
#pragma unroll
    for (int w = 0; w < 4; ++w) {
      float wv = wdoth(sW, hid2, 130 + u * 4 + w);
      o2[w * 5 + 1] = fmaf(wv, m1, o2[w * 5 + 1]);
      o2[w * 5 + 2] = fmaf(wv, m2, o2[w * 5 + 2]);
      o2[w * 5 + 4] = fmaf(wv, m4, o2[w * 5 + 4]);
    }
  }
  // ---- P6 (l1o x Y1 -> l1e), eps, wa=209 (Z1[0]=0) ----
#pragma unroll
  for (int u = 0; u < 3; ++u) {
    float X0 = xs[10 + u * 3 + 0], X1 = xs[10 + u * 3 + 1], X2 = xs[10 + u * 3 + 2];
    float c0 = PS6 * (X1 * Z1[2] - X2 * Z1[1]);
    float c1 = PS6 * (-X0 * Z1[2]);
    float c2 = PS6 * (X0 * Z1[1]);
#pragma unroll
    for (int w = 0; w < 3; ++w) {
      float wv = wdoth(sW, hid2, 209 + u * 3 + w);
      oe[w * 3 + 0] = fmaf(wv, c0, oe[w * 3 + 0]);
      oe[w * 3 + 1] = fmaf(wv, c1, oe[w * 3 + 1]);
      oe[w * 3 + 2] = fmaf(wv, c2, oe[w * 3 + 2]);
    }
  }
  // ---- P7 (l1o x Y1 -> l2), C112, wa=218 (Z1[0]=0) ----
  // ROUND 6 BUG FIX: tm0 = A112f*(X0*Z1[1] + X1*Z1[0]) = A112f*X0*Z1[1]  (NOT zero)
#pragma unroll
  for (int u = 0; u < 3; ++u) {
    float X0 = xs[10 + u * 3 + 0], X1 = xs[10 + u * 3 + 1], X2 = xs[10 + u * 3 + 2];
    float tm0 = PS7 * (A112f * X0 * Z1[1]);
    float tm1 = PS7 * (A112f * (X1 * Z1[2] + X2 * Z1[1]));
    float tm2 = PS7 * (B112f * X2 * Z1[2] - C112f * X1 * Z1[1]);
    float tm3 = PS7 * (A112f * X0 * Z1[2]);
    float tm4 = PS7 * (-A112f * X1 * Z1[1]);
#pragma unroll
    for (int w = 0; w < 4; ++w) {
      float wv = wdoth(sW, hid2, 218 + u * 4 + w);
      o2[w * 5 + 0] = fmaf(wv, tm0, o2[w * 5 + 0]);
      o2[w * 5 + 1] = fmaf(wv, tm1, o2[w * 5 + 1]);
      o2[w * 5 + 2] = fmaf(wv, tm2, o2[w * 5 + 2]);
      o2[w * 5 + 3] = fmaf(wv, tm3, o2[w * 5 + 3]);
      o2[w * 5 + 4] = fmaf(wv, tm4, o2[w * 5 + 4]);
    }
  }
  // ---- P9 (l1e x Y0 -> l1e), wa=239 ----
#pragma unroll
  for (int u = 0; u < 3; ++u) {
    float t0 = PS9 * xs[19 + u * 3 + 0], t1 = PS9 * xs[19 + u * 3 + 1], t2 = PS9 * xs[19 + u * 3 + 2];
#pragma unroll
    for (int w = 0; w < 3; ++w) {
      float wv = wdoth(sW, hid2, 239 + u * 3 + w);
      oe[w * 3 + 0] = fmaf(wv, t0, oe[w * 3 + 0]);
      oe[w * 3 + 1] = fmaf(wv, t1, oe[w * 3 + 1]);
      oe[w * 3 + 2] = fmaf(wv, t2, oe[w * 3 + 2]);
    }
  }
  // ---- P11 (l1e x Y2 -> l1e), C121, wa=257 (Z2[0]=Z2[3]=0) ----
#pragma unroll
  for (int u = 0; u < 3; ++u) {
    float X0 = xs[19 + u * 3 + 0], X1 = xs[19 + u * 3 + 1], X2 = xs[19 + u * 3 + 2];
    float t0 = PS11 * (A112f * X0 * Z2[4] - C112f * X0 * Z2[2]);
    float t1 = PS11 * (A112f * (X2 * Z2[1] - X1 * Z2[4]) - C112f * X1 * Z2[2]);
    float t2 = PS11 * (A112f * X1 * Z2[1] + B112f * X2 * Z2[2]);
#pragma unroll
    for (int w = 0; w < 3; ++w) {
      float wv = wdoth(sW, hid2, 257 + u * 3 + w);
      oe[w * 3 + 0] = fmaf(wv, t0, oe[w * 3 + 0]);
      oe[w * 3 + 1] = fmaf(wv, t1, oe[w * 3 + 1]);
      oe[w * 3 + 2] = fmaf(wv, t2, oe[w * 3 + 2]);
    }
  }
  // ---- P12 (l1e x Y2 -> l2), C122 (antisym), wa=266 (Z2[0]=Z2[3]=0) ----
#pragma unroll
  for (int u = 0; u < 3; ++u) {
    float X0 = xs[19 + u * 3 + 0], X1 = xs[19 + u * 3 + 1], X2 = xs[19 + u * 3 + 2];
    float tm0 = PS12 * (G122f * X1 * Z2[1] + F122f * X2 * Z2[4]);
    float tm1 = PS12 * (-H122f * X0 * Z2[2] - G122f * X0 * Z2[4]);
    float tm2 = PS12 * (H122f * X0 * Z2[1]);
    float tm3 = PS12 * (H122f * X1 * Z2[2] - G122f * X1 * Z2[4] - G122f * X2 * Z2[1]);
    float tm4 = PS12 * (G122f * X0 * Z2[1]);
#pragma unroll
    for (int w = 0; w < 4; ++w) {
      float wv = wdoth(sW, hid2, 266 + u * 4 + w);
      o2[w * 5 + 0] = fmaf(wv, tm0, o2[w * 5 + 0]);
      o2[w * 5 + 1] = fmaf(wv, tm1, o2[w * 5 + 1]);
      o2[w * 5 + 2] = fmaf(wv, tm2, o2[w * 5 + 2]);
      o2[w * 5 + 3] = fmaf(wv, tm3, o2[w * 5 + 3]);
      o2[w * 5 + 4] = fmaf(wv, tm4, o2[w * 5 + 4]);
    }
  }
  // ---- P13 (l2 x Y0 -> l2), wa=278 ----
#pragma unroll
  for (int u = 0; u < 4; ++u) {
    float tm[5];
#pragma unroll
    for (int k = 0; k < 5; ++k) tm[k] = PS13 * xs[28 + u * 5 + k];
#pragma unroll
    for (int w = 0; w < 4; ++w) {
      float wv = wdoth(sW, hid2, 278 + u * 4 + w);
#pragma unroll
      for (int k = 0; k < 5; ++k) o2[w * 5 + k] = fmaf(wv, tm[k], o2[w * 5 + k]);
    }
  }
  // ---- P16 (l2 x Y2 -> l1e), C221 (antisym), wa=346 (Z2[0]=Z2[3]=0) ----
#pragma unroll
  for (int u = 0; u < 4; ++u) {
    float Xa0 = xs[28 + u * 5 + 0], Xa1 = xs[28 + u * 5 + 1], Xa2 = xs[28 + u * 5 + 2];
    float Xa3 = xs[28 + u * 5 + 3], Xa4 = xs[28 + u * 5 + 4];
    float t0 = PS16 * (G122f * (Xa1 * Z2[4] - Xa4 * Z2[1]) + H122f * (Xa1 * Z2[2] - Xa2 * Z2[1]));
    float t1 = PS16 * (G122f * (-Xa0 * Z2[1] + Xa3 * Z2[4]) - H122f * Xa3 * Z2[2]);
    float t2 = PS16 * (G122f * Xa3 * Z2[1] - F122f * Xa0 * Z2[4]);
#pragma unroll
    for (int w = 0; w < 3; ++w) {
      float wv = wdoth(sW, hid2, 346 + u * 3 + w);
      oe[w * 3 + 0] = fmaf(wv, t0, oe[w * 3 + 0]);
      oe[w * 3 + 1] = fmaf(wv, t1, oe[w * 3 + 1]);
      oe[w * 3 + 2] = fmaf(wv, t2, oe[w * 3 + 2]);
    }
  }
  // ---- P17 (l2 x Y2 -> l2), C222 (Gaunt), wa=358 (full formulas; Z2[0]=Z2[3]=0 folds) ----
#pragma unroll
  for (int u = 0; u < 4; ++u) {
    float Xa0 = xs[28 + u * 5 + 0], Xa1 = xs[28 + u * 5 + 1], Xa2 = xs[28 + u * 5 + 2];
    float Xa3 = xs[28 + u * 5 + 3], Xa4 = xs[28 + u * 5 + 4];
    float tm[5];
    tm[0] = PS17 * (-2.f * P222f * Xa0 * Z2[2] + SP222f * Xa3 * Z2[1]);
    tm[1] = PS17 * (P222f * (Xa1 * Z2[2] + Xa2 * Z2[1]) + SP222f * (-Xa1 * Z2[4] - Xa4 * Z2[1]));
    tm[2] = PS17 * (P222f * Xa1 * Z2[1] + 2.f * P222f * (Xa2 * Z2[2] - Xa4 * Z2[4]));
    tm[3] = PS17 * (P222f * Xa3 * Z2[2] + SP222f * (Xa3 * Z2[4] + Xa0 * Z2[1]));
    tm[4] = PS17 * (SP222f * (-Xa1 * Z2[1]) - 2.f * P222f * (Xa2 * Z2[4] + Xa4 * Z2[2]));
#pragma unroll
    for (int w = 0; w < 4; ++w) {
      float wv = wdoth(sW, hid2, 358 + u * 4 + w);
#pragma unroll
      for (int k = 0; k < 5; ++k) o2[w * 5 + k] = fmaf(wv, tm[k], o2[w * 5 + k]);
    }
  }

  // ---- store o[19:48] into CSR-ordered MSG row ----
  float* mp = MSG + (size_t)epos[t] * 48;
  mp[19] = oe[0];
  float pk[28];
#pragma unroll
  for (int j = 0; j < 8; ++j) pk[j] = oe[1 + j];
#pragma unroll
  for (int j = 0; j < 20; ++j) pk[8 + j] = o2[j];
#pragma unroll
  for (int q = 0; q < 7; ++q) ((float4*)(mp + 20))[q] = ((float4*)pk)[q];
}

// =================== CSR gather: one wave per node, lane = feature; contiguous rows ===================
__global__ void k_agg(const int* __restrict__ off, const float* __restrict__ MSG,
                      float* __restrict__ AGG) {
  int gt = blockIdx.x * blockDim.x + threadIdx.x;
  int wid = gt >> 6;          // node
  int lane = threadIdx.x & 63;
  if (wid >= BN) return;
  int a = off[wid], bnd = off[wid + 1];
  if (lane < 48) {
    float s = 0.f;
    for (int k = a; k < bnd; ++k) s += MSG[(size_t)k * 48 + lane];
    AGG[(size_t)wid * 48 + lane] = s;
  }
}

// =================== self-term + norm_act ===================
__global__ void k_post(const float* __restrict__ AGG, const float* __restrict__ hin,
                       const float* __restrict__ w0, const float* __restrict__ b0,
                       const float* __restrict__ w1o, const float* __restrict__ w1e,
                       const float* __restrict__ w2e, const float* __restrict__ mask_n,
                       float* __restrict__ hout) {
  int t = blockIdx.x * blockDim.x + threadIdx.x;
  if (t >= BN) return;
  float h[48], li[48], s[48];
  const float4* hp = (const float4*)(hin + (size_t)t * 48);
#pragma unroll
  for (int q = 0; q < 12; ++q) ((float4*)h)[q] = hp[q];
  lin48(h, w0, b0, w1o, w1e, w2e, li);
  const float4* gp = (const float4*)(AGG + (size_t)t * 48);
#pragma unroll
  for (int q = 0; q < 12; ++q) ((float4*)s)[q] = gp[q];
#pragma unroll
  for (int j = 0; j < 48; ++j) s[j] += li[j];
  float mk = mask_n[t];
  float r[48];
#pragma unroll
  for (int j = 0; j < 10; ++j) {
    float v = s[j];
    r[j] = v * sigm(sqrtf(v * v + 1e-12f)) * mk;
  }
#pragma unroll
  for (int u = 0; u < 3; ++u) {
    float n1 = 0.f, n2 = 0.f;
#pragma unroll
    for (int m = 0; m < 3; ++m) {
      n1 = fmaf(s[10 + u * 3 + m], s[10 + u * 3 + m], n1);
      n2 = fmaf(s[19 + u * 3 + m], s[19 + u * 3 + m], n2);
    }
    float f1 = sigm(sqrtf(n1 + 1e-12f)) * mk;
    float f2 = sigm(sqrtf(n2 + 1e-12f)) * mk;
#pragma unroll
    for (int m = 0; m < 3; ++m) {
      r[10 + u * 3 + m] = s[10 + u * 3 + m] * f1;
      r[19 + u * 3 + m] = s[19 + u * 3 + m] * f2;
    }
  }
#pragma unroll
  for (int u = 0; u < 4; ++u) {
    float n3 = 0.f;
#pragma unroll
    for (int m = 0; m < 5; ++m) n3 = fmaf(s[28 + u * 5 + m], s[28 + u * 5 + m], n3);
    float f3 = sigm(sqrtf(n3 + 1e-12f)) * mk;
#pragma unroll
    for (int m = 0; m < 5; ++m) r[28 + u * 5 + m] = s[28 + u * 5 + m] * f3;
  }
  float4* op = (float4*)(hout + (size_t)t * 48);
#pragma unroll
  for (int q = 0; q < 12; ++q) op[q] = ((float4*)r)[q];
}

// =================== readout ===================
__global__ void k_out(const float* __restrict__ h, const int* __restrict__ centers,
                      const float* __restrict__ sw0, const float* __restrict__ sb0,
                      const float* __restrict__ sw2, float* __restrict__ out) {
  int b = threadIdx.x;
  if (b >= Bb) return;
  int c = centers[b];
  const float* hc = h + ((size_t)(b * Nn + c)) * 48;
  float acc = 0.f;
#pragma unroll
  for (int u = 0; u < 10; ++u) acc = fmaf(hc[u], sw0[u], acc);
  float tr = acc * RS10f + sb0[0];
  float s2[5];
#pragma unroll
  for (int m = 0; m < 5; ++m) {
    float a = 0.f;
#pragma unroll
    for (int u = 0; u < 4; ++u) a = fmaf(hc[28 + u * 5 + m], sw2[u], a);
    s2[m] = a * 0.5f;
  }
  float a0 = s2[0], a2c = s2[1], a2s = s2[2], a1c = s2[3], a1s = s2[4];
  const float is6 = 0.4082482904638630f;
  const float is2 = 0.7071067811865476f;
  const float i3 = 0.3333333333333333f;
  out[b * 6 + 0] = -a0 * is6 + a2c * is2 + tr * i3;
  out[b * 6 + 1] = a2s;
  out[b * 6 + 2] = a1c;
  out[b * 6 + 3] = -a0 * is6 - a2c * is2 + tr * i3;
  out[b * 6 + 4] = a1s;
  out[b * 6 + 5] = 2.f * a0 * is6 + tr * i3;
}

// =================== host launch ===================
extern "C" void kernel_launch(void* const* d_in, const int* in_sizes, int n_in,
                              void* d_out, int out_size, void* d_ws, size_t ws_size,
                              hipStream_t stream) {
  const float* x_nodes = (const float*)d_in[0];
  const float* e_attr2 = (const float*)d_in[1];
  const float* mask_n  = (const float*)d_in[2];
  const float* mask_e  = (const float*)d_in[3];
  const float* enc_w0  = (const float*)d_in[4];
  const float* enc_b0  = (const float*)d_in[5];
  const float* enc_w1e = (const float*)d_in[6];
  const float* enc_w2e = (const float*)d_in[7];
  const float* li_w0   = (const float*)d_in[8];
  const float* li_b0   = (const float*)d_in[9];
  const float* li_w1o  = (const float*)d_in[10];
  const float* li_w1e  = (const float*)d_in[11];
  const float* li_w2e  = (const float*)d_in[12];
  const float* rad_w1  = (const float*)d_in[13];
  const float* rad_w2  = (const float*)d_in[14];
  const float* lr_w0   = (const float*)d_in[15];
  const float* lr_b0   = (const float*)d_in[16];
  const float* lr_w1o  = (const float*)d_in[17];
  const float* lr_w1e  = (const float*)d_in[18];
  const float* lr_w2e  = (const float*)d_in[19];
  const float* sym_w0  = (const float*)d_in[20];
  const float* sym_b0  = (const float*)d_in[21];
  const float* sym_w2e = (const float*)d_in[22];
  const int* e_src = (const int*)d_in[23];
  const int* e_dst = (const int*)d_in[24];
  const int* centers = (const int*)d_in[25];
  float* out = (float*)d_out;

  float* ws  = (float*)d_ws;
  float* hA  = ws;
  float* hB  = hA + (size_t)BN * 48;
  float* HIN = hB + (size_t)BN * 48;
  float* AGG = HIN + (size_t)BN * 48;
  float* MSG = AGG + (size_t)BN * 48;                 // BE*48 f32 = 50.3 MB
  uint32_t* R2T16 = (uint32_t*)(MSG + (size_t)BE * 48);
  int* deg    = (int*)(R2T16 + 2 * NW * 16);
  int* off    = deg + BN;        // BN+1
  int* cursor = off + BN + 1;
  int* bsum   = cursor + BN;     // 128
  int* boff   = bsum + 128;      // 128
  int* epos   = boff + 128;      // BE

  k_tr<<<3, 256, 0, stream>>>(rad_w2, R2T16);
  k_enc<<<BN / 256, 256, 0, stream>>>(x_nodes, mask_n, enc_w0, enc_b0, enc_w1e, enc_w2e, hA);

  // CSR of e_dst (constant across layers)
  (void)hipMemsetAsync(deg, 0, (size_t)BN * sizeof(int), stream);
  k_count<<<BE / 256, 256, 0, stream>>>(e_dst, deg);
  k_scan_block<<<BN / 256, 256, 0, stream>>>(deg, off, bsum);
  k_scan_bsum<<<1, 128, 0, stream>>>(bsum, boff);
  k_scan_add<<<BN / 256, 256, 0, stream>>>(boff, off, cursor);
  k_fill<<<BE / 256, 256, 0, stream>>>(e_dst, cursor, epos);

  float* hcur = hA;
  float* hnext = hB;
  for (int l = 0; l < 2; ++l) {
    k_lin<<<BN / 256, 256, 0, stream>>>(hcur, li_w0 + l * 100, li_b0 + l * 10,
                                        li_w1o + l * 9, li_w1e + l * 9, li_w2e + l * 16, HIN);
    k_msgA<<<BE / 256, 256, 0, stream>>>(HIN, e_attr2, mask_e, rad_w1 + l * 32,
                                         R2T16 + (size_t)l * NW * 16, e_src, epos, MSG);
    k_msgB<<<BE / 256, 256, 0, stream>>>(HIN, e_attr2, mask_e, rad_w1 + l * 32,
                                         R2T16 + (size_t)l * NW * 16, e_src, epos, MSG);
    k_agg<<<(BN * 64) / 256, 256, 0, stream>>>(off, MSG, AGG);
    k_post<<<BN / 256, 256, 0, stream>>>(AGG, hcur, lr_w0 + l * 100, lr_b0 + l * 10,
                                         lr_w1o + l * 9, lr_w1e + l * 9, lr_w2e + l * 16,
                                         mask_n, hnext);
    float* tswap = hcur; hcur = hnext; hnext = tswap;
  }
  k_out<<<1, 64, 0, stream>>>(hcur, centers, sym_w0, sym_b0, sym_w2e, out);
}

// Round 9
// 1079.525 us; speedup vs baseline: 1.2457x; 1.2457x over previous
//
#include <hip/hip_runtime.h>
#include <hip/hip_fp16.h>
#include <math.h>
#include <stdint.h>

// =================== problem constants ===================
constexpr int Bb = 4;
constexpr int Nn = 8192;
constexpr int Ee = 65536;
constexpr int BN = Bb * Nn;   // 32768 nodes
constexpr int BE = Bb * Ee;   // 262144 edges
constexpr int NW = 374;       // radial weight columns
constexpr int NWU = NW * 16;  // u32 (f16x2) elements in the table

// w3j tie-break signs — VERIFIED round 1 (absmax 0.0)
#define S111 (+1.0f)
#define S122 (-1.0f)
#define S221 (-1.0f)
#define S222 (-1.0f)

#define SQ3f   1.7320508075688772f
#define SQ15f  3.872983346207417f
#define HSQ5f  1.118033988749895f
#define HSQ15f 1.9364916731037085f
#define RS10f  0.31622776601683794f
#define RS3f   0.5773502691896258f
#define RS32f  0.17677669529663687f
#define K1f    0.5773502691896258f
#define K2f    0.4472135954999579f
#define K6f    0.40824829046386296f
#define A0f    0.24253562503633297f
#define A1f    0.3612106650782119f
#define A2f    0.4803844614152614f
#define A3f    0.4564354645876384f
#define A112f  0.31622776601683794f
#define B112f  0.3651483716701107f
#define C112f  0.18257418583505536f
#define G122f  0.18257418583505536f
#define H122f  0.31622776601683794f
#define F122f  0.3651483716701107f
#define P222f  0.11952286093343936f
#define SP222f 0.20701966780270626f

#define PS1  (A0f*RS32f)
#define PS2  (A1f*RS32f*K1f)
#define PS3  (A3f*RS32f*K2f)
#define PS4  (A1f*RS32f*K1f)
#define PS5  (A0f*RS32f*K1f)
#define PS6  (A2f*RS32f*K6f*S111)
#define PS7  (A3f*RS32f)
#define PS8  (A1f*RS32f)
#define PS9  (A2f*RS32f*K1f)
#define PS10 (A1f*RS32f*K6f*S111)
#define PS11 (A2f*RS32f)
#define PS12 (A3f*RS32f*S122)
#define PS13 (A3f*RS32f*K2f)
#define PS14 (A1f*RS32f)
#define PS15 (A0f*RS32f*K2f)
#define PS16 (A2f*RS32f*S221)
#define PS17 (A3f*RS32f*S222)

typedef _Float16 h2v __attribute__((ext_vector_type(2)));   // fdot2 operand type
typedef __fp16   p2v __attribute__((ext_vector_type(2)));   // cvt_pkrtz result type
union H2U { uint32_t u; h2v h; p2v p; };

__device__ __forceinline__ float sigm(float z) { return 1.f / (1.f + __expf(-z)); }

// dot over 32 radial-hidden units; LDS broadcast reads; 2 accumulators halve the dep chain
__device__ __forceinline__ float wdoth(const uint32_t* sW,
                                       const uint32_t hid2[16], int col) {
  float a0 = 0.f, a1 = 0.f;
  const uint32_t* p = sW + col * 16;
#pragma unroll
  for (int q = 0; q < 16; q += 2) {
    H2U x0; x0.u = hid2[q];     H2U y0; y0.u = p[q];
    H2U x1; x1.u = hid2[q + 1]; H2U y1; y1.u = p[q + 1];
#if defined(__has_builtin) && __has_builtin(__builtin_amdgcn_fdot2)
    a0 = __builtin_amdgcn_fdot2(x0.h, y0.h, a0, false);
    a1 = __builtin_amdgcn_fdot2(x1.h, y1.h, a1, false);
#else
    a0 = fmaf((float)x0.h[0], (float)y0.h[0], a0);
    a0 = fmaf((float)x0.h[1], (float)y0.h[1], a0);
    a1 = fmaf((float)x1.h[0], (float)y1.h[0], a1);
    a1 = fmaf((float)x1.h[1], (float)y1.h[1], a1);
#endif
  }
  return a0 + a1;
}

// =================== transpose+convert rad_w2 -> f16 packed [L][374][16] ===================
__global__ void k_tr(const float* __restrict__ R2all, uint32_t* __restrict__ T) {
  int t = blockIdx.x * blockDim.x + threadIdx.x;
  if (t >= 2 * NW) return;
  int l = t / NW, c = t - l * NW;
  const float* src = R2all + (size_t)l * 32 * NW + c;
  uint32_t* dst = T + (size_t)t * 16;
#pragma unroll
  for (int p = 0; p < 16; ++p) {
    H2U u;
    u.p = __builtin_amdgcn_cvt_pkrtz(src[(size_t)(2 * p) * NW], src[(size_t)(2 * p + 1) * NW]);
    dst[p] = u.u;
  }
}

// =================== encoder ===================
__global__ void k_enc(const float* __restrict__ xn, const float* __restrict__ mask_n,
                      const float* __restrict__ ew0, const float* __restrict__ eb0,
                      const float* __restrict__ ew1e, const float* __restrict__ ew2e,
                      float* __restrict__ h) {
  int t = blockIdx.x * blockDim.x + threadIdx.x;
  if (t >= BN) return;
  const float* x9 = xn + (size_t)t * 9;
  float U00 = x9[0], U01 = x9[1], U02 = x9[2];
  float U10 = x9[3], U11 = x9[4], U12 = x9[5];
  float U20 = x9[6], U21 = x9[7], U22 = x9[8];
  float tr = U00 + U11 + U22;
  float a[5];
  a[0] = (2.f * U22 - U00 - U11) * 0.4082482904638630f;
  a[1] = (U00 - U11) * 0.7071067811865476f;
  a[2] = 0.7071067811865476f * (U01 + U10);
  a[3] = 0.7071067811865476f * (U02 + U20);
  a[4] = 0.7071067811865476f * (U12 + U21);
  float om[3];
  om[0] = 0.5f * (U12 - U21);
  om[1] = 0.5f * (U20 - U02);
  om[2] = 0.5f * (U01 - U10);
  float mk = mask_n[t];
  float o[48];
#pragma unroll
  for (int j = 0; j < 10; ++j) o[j] = (tr * ew0[j] + eb0[j]) * mk;
#pragma unroll
  for (int j = 10; j < 19; ++j) o[j] = 0.f;
#pragma unroll
  for (int w = 0; w < 3; ++w)
#pragma unroll
    for (int mm = 0; mm < 3; ++mm) o[19 + w * 3 + mm] = om[mm] * ew1e[w] * mk;
#pragma unroll
  for (int w = 0; w < 4; ++w)
#pragma unroll
    for (int mm = 0; mm < 5; ++mm) o[28 + w * 5 + mm] = a[mm] * ew2e[w] * mk;
  float4* hp = (float4*)(h + (size_t)t * 48);
#pragma unroll
  for (int q = 0; q < 12; ++q) hp[q] = ((float4*)o)[q];
}

// =================== per-channel linear (lin_hid) ===================
__device__ __forceinline__ void lin48(const float h[48], const float* __restrict__ w0,
                                      const float* __restrict__ b0, const float* __restrict__ w1o,
                                      const float* __restrict__ w1e, const float* __restrict__ w2e,
                                      float o[48]) {
#pragma unroll
  for (int j = 0; j < 10; ++j) {
    float s = 0.f;
#pragma unroll
    for (int u = 0; u < 10; ++u) s = fmaf(h[u], w0[u * 10 + j], s);
    o[j] = s * RS10f + b0[j];
  }
#pragma unroll
  for (int w = 0; w < 3; ++w) {
#pragma unroll
    for (int m = 0; m < 3; ++m) {
      float s1 = 0.f, s2 = 0.f;
#pragma unroll
      for (int u = 0; u < 3; ++u) {
        s1 = fmaf(h[10 + u * 3 + m], w1o[u * 3 + w], s1);
        s2 = fmaf(h[19 + u * 3 + m], w1e[u * 3 + w], s2);
      }
      o[10 + w * 3 + m] = s1 * RS3f;
      o[19 + w * 3 + m] = s2 * RS3f;
    }
  }
#pragma unroll
  for (int w = 0; w < 4; ++w) {
#pragma unroll
    for (int m = 0; m < 5; ++m) {
      float s = 0.f;
#pragma unroll
      for (int u = 0; u < 4; ++u) s = fmaf(h[28 + u * 5 + m], w2e[u * 4 + w], s);
      o[28 + w * 5 + m] = s * 0.5f;
    }
  }
}

__global__ void k_lin(const float* __restrict__ hin, const float* __restrict__ w0,
                      const float* __restrict__ b0, const float* __restrict__ w1o,
                      const float* __restrict__ w1e, const float* __restrict__ w2e,
                      float* __restrict__ hout) {
  int t = blockIdx.x * blockDim.x + threadIdx.x;
  if (t >= BN) return;
  float h[48], o[48];
  const float4* hp = (const float4*)(hin + (size_t)t * 48);
#pragma unroll
  for (int q = 0; q < 12; ++q) ((float4*)h)[q] = hp[q];
  lin48(h, w0, b0, w1o, w1e, w2e, o);
  float4* op = (float4*)(hout + (size_t)t * 48);
#pragma unroll
  for (int q = 0; q < 12; ++q) op[q] = ((float4*)o)[q];
}

// =================== CSR build (e_dst is constant across layers) ===================
__global__ void k_count(const int* __restrict__ edst, int* __restrict__ deg) {
  int t = blockIdx.x * blockDim.x + threadIdx.x;
  if (t >= BE) return;
  int b = t >> 16;
  atomicAdd(&deg[edst[t] + (b << 13)], 1);
}

__global__ void k_scan_block(const int* __restrict__ deg, int* __restrict__ off,
                             int* __restrict__ bsum) {
  __shared__ int sh[256];
  int i = threadIdx.x, g = blockIdx.x * 256 + i;
  int v = deg[g];
  sh[i] = v;
  __syncthreads();
  for (int d = 1; d < 256; d <<= 1) {
    int tv = (i >= d) ? sh[i - d] : 0;
    __syncthreads();
    sh[i] += tv;
    __syncthreads();
  }
  off[g] = sh[i] - v;  // exclusive within block
  if (i == 255) bsum[blockIdx.x] = sh[i];
}

__global__ void k_scan_bsum(int* __restrict__ bsum, int* __restrict__ boff) {
  __shared__ int sh[128];
  int i = threadIdx.x;
  int v = bsum[i];
  sh[i] = v;
  __syncthreads();
  for (int d = 1; d < 128; d <<= 1) {
    int tv = (i >= d) ? sh[i - d] : 0;
    __syncthreads();
    sh[i] += tv;
    __syncthreads();
  }
  boff[i] = sh[i] - v;  // exclusive
}

__global__ void k_scan_add(const int* __restrict__ boff, int* __restrict__ off,
                           int* __restrict__ cursor) {
  int g = blockIdx.x * 256 + threadIdx.x;
  int v = off[g] + boff[blockIdx.x];
  off[g] = v;
  cursor[g] = v;
  if (g == 0) off[BN] = BE;
}

// epos[t] = CSR slot of edge t -> k_msg stores in CSR order, k_agg reads contiguous
__global__ void k_fill(const int* __restrict__ edst, int* __restrict__ cursor,
                       int* __restrict__ epos) {
  int t = blockIdx.x * blockDim.x + threadIdx.x;
  if (t >= BE) return;
  int b = t >> 16;
  int d = edst[t] + (b << 13);
  int pos = atomicAdd(&cursor[d], 1);
  epos[t] = pos;
}

// =================== message kernel: ONE kernel, TWO internal phases ===================
// Round 7 post-mortem: __launch_bounds__(256,4) let the allocator chase 8 waves/EU
// -> VGPR 64 + massive scratch spill (FETCH 229MB / WRITE 409MB per dispatch).
// Fix: pin waves/EU to exactly 4 (VGPR budget 128) and split the body into two
// sequential phases (store o[0:19], then o[19:48]) so the live set fits 128.
__global__ __launch_bounds__(256)
__attribute__((amdgpu_waves_per_eu(4, 4)))
void k_msg(
    const float* __restrict__ HIN, const float* __restrict__ e_attr2,
    const float* __restrict__ mask_e, const float* __restrict__ rw1,
    const uint32_t* __restrict__ W16, const int* __restrict__ esrc,
    const int* __restrict__ epos, float* __restrict__ MSG) {
  __shared__ __align__(16) uint32_t sW[NWU];   // 23936 B
  int tid = threadIdx.x;
  {
    const uint4* src4 = (const uint4*)W16;
    uint4* dst4 = (uint4*)sW;
#pragma unroll
    for (int i = 0; i < 6; ++i) {
      int idx = tid + i * 256;
      if (idx < NWU / 4) dst4[idx] = src4[idx];
    }
  }
  __syncthreads();

  int t = blockIdx.x * blockDim.x + tid;
  if (t >= BE) return;
  int b = t >> 16;
  int srow = esrc[t] + (b << 13);

  float mke = mask_e[t];
  float ey = e_attr2[2 * t] * mke;
  float ez = e_attr2[2 * t + 1] * mke;
  float rn = sqrtf(ey * ey + ez * ez) + 1e-8f;
  float yy = ey / rn, zz = ez / rn;
  const float Z1[3] = {0.f, SQ3f * yy, SQ3f * zz};
  const float Z2[5] = {0.f, SQ15f * yy * zz, HSQ5f * (2.f * zz * zz - yy * yy),
                       0.f, -HSQ15f * yy * yy};
  uint32_t hid2[16];
#pragma unroll
  for (int q = 0; q < 16; ++q) {
    float z0 = rn * rw1[2 * q];
    float z1 = rn * rw1[2 * q + 1];
    H2U u;
    u.p = __builtin_amdgcn_cvt_pkrtz(z0 * sigm(z0), z1 * sigm(z1));
    hid2[q] = u.u;
  }
  float xs[48];
  {
    const float4* hp = (const float4*)(HIN + (size_t)srow * 48);
#pragma unroll
    for (int q = 0; q < 12; ++q) ((float4*)xs)[q] = hp[q];
  }
  float* mp = MSG + (size_t)epos[t] * 48;

  // ========== PHASE 1: o[0:19] = l0 + l1o ==========
  {
    float o[19];
#pragma unroll
    for (int j = 0; j < 19; ++j) o[j] = 0.f;

    // ---- P1 (l0 x Y0 -> l0), wa=0 ----
#pragma unroll
    for (int u = 0; u < 10; ++u) {
      float xu = PS1 * xs[u];
#pragma unroll
      for (int w = 0; w < 10; ++w) o[w] = fmaf(wdoth(sW, hid2, u * 10 + w), xu, o[w]);
    }
    // ---- P2 (l0 x Y1 -> l1o), wa=100 (t0 = 0) ----
#pragma unroll
    for (int u = 0; u < 10; ++u) {
      float xu = PS2 * xs[u];
      float t1 = xu * Z1[1], t2 = xu * Z1[2];
#pragma unroll
      for (int w = 0; w < 3; ++w) {
        float wv = wdoth(sW, hid2, 100 + u * 3 + w);
        o[10 + w * 3 + 1] = fmaf(wv, t1, o[10 + w * 3 + 1]);
        o[10 + w * 3 + 2] = fmaf(wv, t2, o[10 + w * 3 + 2]);
      }
    }
    // ---- P4 (l1o x Y0 -> l1o), wa=170 ----
#pragma unroll
    for (int u = 0; u < 3; ++u) {
      float t0 = PS4 * xs[10 + u * 3 + 0], t1 = PS4 * xs[10 + u * 3 + 1], t2 = PS4 * xs[10 + u * 3 + 2];
#pragma unroll
      for (int w = 0; w < 3; ++w) {
        float wv = wdoth(sW, hid2, 170 + u * 3 + w);
        o[10 + w * 3 + 0] = fmaf(wv, t0, o[10 + w * 3 + 0]);
        o[10 + w * 3 + 1] = fmaf(wv, t1, o[10 + w * 3 + 1]);
        o[10 + w * 3 + 2] = fmaf(wv, t2, o[10 + w * 3 + 2]);
      }
    }
    // ---- P5 (l1o x Y1 -> l0), wa=179 ----
#pragma unroll
    for (int u = 0; u < 3; ++u) {
      float s = PS5 * (xs[10 + u * 3 + 1] * Z1[1] + xs[10 + u * 3 + 2] * Z1[2]);
#pragma unroll
      for (int w = 0; w < 10; ++w) o[w] = fmaf(wdoth(sW, hid2, 179 + u * 10 + w), s, o[w]);
    }
    // ---- P8 (l1o x Y2 -> l1o), C121, wa=230 ----
#pragma unroll
    for (int u = 0; u < 3; ++u) {
      float X0 = xs[10 + u * 3 + 0], X1 = xs[10 + u * 3 + 1], X2 = xs[10 + u * 3 + 2];
      float t0 = PS8 * (A112f * X0 * Z2[4] - C112f * X0 * Z2[2]);
      float t1 = PS8 * (A112f * (X2 * Z2[1] - X1 * Z2[4]) - C112f * X1 * Z2[2]);
      float t2 = PS8 * (A112f * X1 * Z2[1] + B112f * X2 * Z2[2]);
#pragma unroll
      for (int w = 0; w < 3; ++w) {
        float wv = wdoth(sW, hid2, 230 + u * 3 + w);
        o[10 + w * 3 + 0] = fmaf(wv, t0, o[10 + w * 3 + 0]);
        o[10 + w * 3 + 1] = fmaf(wv, t1, o[10 + w * 3 + 1]);
        o[10 + w * 3 + 2] = fmaf(wv, t2, o[10 + w * 3 + 2]);
      }
    }
    // ---- P10 (l1e x Y1 -> l1o), eps, wa=248 ----
#pragma unroll
    for (int u = 0; u < 3; ++u) {
      float X0 = xs[19 + u * 3 + 0], X1 = xs[19 + u * 3 + 1], X2 = xs[19 + u * 3 + 2];
      float c0 = PS10 * (X1 * Z1[2] - X2 * Z1[1]);
      float c1 = PS10 * (-X0 * Z1[2]);
      float c2 = PS10 * (X0 * Z1[1]);
#pragma unroll
      for (int w = 0; w < 3; ++w) {
        float wv = wdoth(sW, hid2, 248 + u * 3 + w);
        o[10 + w * 3 + 0] = fmaf(wv, c0, o[10 + w * 3 + 0]);
        o[10 + w * 3 + 1] = fmaf(wv, c1, o[10 + w * 3 + 1]);
        o[10 + w * 3 + 2] = fmaf(wv, c2, o[10 + w * 3 + 2]);
      }
    }
    // ---- P14 (l2 x Y1 -> l1o), C211, wa=294 ----
#pragma unroll
    for (int u = 0; u < 4; ++u) {
      float Xa0 = xs[28 + u * 5 + 0], Xa1 = xs[28 + u * 5 + 1], Xa2 = xs[28 + u * 5 + 2];
      float Xa3 = xs[28 + u * 5 + 3], Xa4 = xs[28 + u * 5 + 4];
      float t0 = PS14 * (A112f * (Z1[1] * Xa0 + Z1[2] * Xa3));
      float t1 = PS14 * (A112f * (Z1[2] * Xa1 - Z1[1] * Xa4) - C112f * Z1[1] * Xa2);
      float t2 = PS14 * (A112f * Z1[1] * Xa1 + B112f * Z1[2] * Xa2);
#pragma unroll
      for (int w = 0; w < 3; ++w) {
        float wv = wdoth(sW, hid2, 294 + u * 3 + w);
        o[10 + w * 3 + 0] = fmaf(wv, t0, o[10 + w * 3 + 0]);
        o[10 + w * 3 + 1] = fmaf(wv, t1, o[10 + w * 3 + 1]);
        o[10 + w * 3 + 2] = fmaf(wv, t2, o[10 + w * 3 + 2]);
      }
    }
    // ---- P15 (l2 x Y2 -> l0), wa=306 ----
#pragma unroll
    for (int u = 0; u < 4; ++u) {
      float s = PS15 * (xs[28 + u * 5 + 1] * Z2[1] + xs[28 + u * 5 + 2] * Z2[2] + xs[28 + u * 5 + 4] * Z2[4]);
#pragma unroll
      for (int w = 0; w < 10; ++w) o[w] = fmaf(wdoth(sW, hid2, 306 + u * 10 + w), s, o[w]);
    }

    // store o[0:19]
#pragma unroll
    for (int q = 0; q < 4; ++q) ((float4*)mp)[q] = ((float4*)o)[q];
    mp[16] = o[16]; mp[17] = o[17]; mp[18] = o[18];
  }

  __builtin_amdgcn_sched_barrier(0);  // keep phase-2 code from being hoisted into phase 1

  // ========== PHASE 2: o[19:48] = l1e + l2 ==========
  {
    float oe[9];
    float o2[20];
#pragma unroll
    for (int j = 0; j < 9; ++j) oe[j] = 0.f;
#pragma unroll
    for (int j = 0; j < 20; ++j) o2[j] = 0.f;

    // ---- P3 (l0 x Y2 -> l2), wa=130 ----
#pragma unroll
    for (int u = 0; u < 10; ++u) {
      float xu = PS3 * xs[u];
      float m1 = xu * Z2[1], m2 = xu * Z2[2], m4 = xu * Z2[4];
#pragma unroll
      for (int w = 0; w < 4; ++w) {
        float wv = wdoth(sW, hid2, 130 + u * 4 + w);
        o2[w * 5 + 1] = fmaf(wv, m1, o2[w * 5 + 1]);
        o2[w * 5 + 2] = fmaf(wv, m2, o2[w * 5 + 2]);
        o2[w * 5 + 4] = fmaf(wv, m4, o2[w * 5 + 4]);
      }
    }
    // ---- P6 (l1o x Y1 -> l1e), eps, wa=209 ----
#pragma unroll
    for (int u = 0; u < 3; ++u) {
      float X0 = xs[10 + u * 3 + 0], X1 = xs[10 + u * 3 + 1], X2 = xs[10 + u * 3 + 2];
      float c0 = PS6 * (X1 * Z1[2] - X2 * Z1[1]);
      float c1 = PS6 * (-X0 * Z1[2]);
      float c2 = PS6 * (X0 * Z1[1]);
#pragma unroll
      for (int w = 0; w < 3; ++w) {
        float wv = wdoth(sW, hid2, 209 + u * 3 + w);
        oe[w * 3 + 0] = fmaf(wv, c0, oe[w * 3 + 0]);
        oe[w * 3 + 1] = fmaf(wv, c1, oe[w * 3 + 1]);
        oe[w * 3 + 2] = fmaf(wv, c2, oe[w * 3 + 2]);
      }
    }
    // ---- P7 (l1o x Y1 -> l2), C112, wa=218 (tm0 = A112f*X0*Z1[1], round-6 bug fixed) ----
#pragma unroll
    for (int u = 0; u < 3; ++u) {
      float X0 = xs[10 + u * 3 + 0], X1 = xs[10 + u * 3 + 1], X2 = xs[10 + u * 3 + 2];
      float tm0 = PS7 * (A112f * X0 * Z1[1]);
      float tm1 = PS7 * (A112f * (X1 * Z1[2] + X2 * Z1[1]));
      float tm2 = PS7 * (B112f * X2 * Z1[2] - C112f * X1 * Z1[1]);
      float tm3 = PS7 * (A112f * X0 * Z1[2]);
      float tm4 = PS7 * (-A112f * X1 * Z1[1]);
#pragma unroll
      for (int w = 0; w < 4; ++w) {
        float wv = wdoth(sW, hid2, 218 + u * 4 + w);
        o2[w * 5 + 0] = fmaf(wv, tm0, o2[w * 5 + 0]);
        o2[w * 5 + 1] = fmaf(wv, tm1, o2[w * 5 + 1]);
        o2[w * 5 + 2] = fmaf(wv, tm2, o2[w * 5 + 2]);
        o2[w * 5 + 3] = fmaf(wv, tm3, o2[w * 5 + 3]);
        o2[w * 5 + 4] = fmaf(wv, tm4, o2[w * 5 + 4]);
      }
    }
    // ---- P9 (l1e x Y0 -> l1e), wa=239 ----
#pragma unroll
    for (int u = 0; u < 3; ++u) {
      float t0 = PS9 * xs[19 + u * 3 + 0], t1 = PS9 * xs[19 + u * 3 + 1], t2 = PS9 * xs[19 + u * 3 + 2];
#pragma unroll
      for (int w = 0; w < 3; ++w) {
        float wv = wdoth(sW, hid2, 239 + u * 3 + w);
        oe[w * 3 + 0] = fmaf(wv, t0, oe[w * 3 + 0]);
        oe[w * 3 + 1] = fmaf(wv, t1, oe[w * 3 + 1]);
        oe[w * 3 + 2] = fmaf(wv, t2, oe[w * 3 + 2]);
      }
    }
    // ---- P11 (l1e x Y2 -> l1e), C121, wa=257 ----
#pragma unroll
    for (int u = 0; u < 3; ++u) {
      float X0 = xs[19 + u * 3 + 0], X1 = xs[19 + u * 3 + 1], X2 = xs[19 + u * 3 + 2];
      float t0 = PS11 * (A112f * X0 * Z2[4] - C112f * X0 * Z2[2]);
      float t1 = PS11 * (A112f * (X2 * Z2[1] - X1 * Z2[4]) - C112f * X1 * Z2[2]);
      float t2 = PS11 * (A112f * X1 * Z2[1] + B112f * X2 * Z2[2]);
#pragma unroll
      for (int w = 0; w < 3; ++w) {
        float wv = wdoth(sW, hid2, 257 + u * 3 + w);
        oe[w * 3 + 0] = fmaf(wv, t0, oe[w * 3 + 0]);
        oe[w * 3 + 1] = fmaf(wv, t1, oe[w * 3 + 1]);
        oe[w * 3 + 2] = fmaf(wv, t2, oe[w * 3 + 2]);
      }
    }
    // ---- P12 (l1e x Y2 -> l2), C122 (antisym), wa=266 ----
#pragma unroll
    for (int u = 0; u < 3; ++u) {
      float X0 = xs[19 + u * 3 + 0], X1 = xs[19 + u * 3 + 1], X2 = xs[19 + u * 3 + 2];
      float tm0 = PS12 * (G122f * X1 * Z2[1] + F122f * X2 * Z2[4]);
      float tm1 = PS12 * (-H122f * X0 * Z2[2] - G122f * X0 * Z2[4]);
      float tm2 = PS12 * (H122f * X0 * Z2[1]);
      float tm3 = PS12 * (H122f * X1 * Z2[2] - G122f * X1 * Z2[4] - G122f * X2 * Z2[1]);
      float tm4 = PS12 * (G122f * X0 * Z2[1]);
#pragma unroll
      for (int w = 0; w < 4; ++w) {
        float wv = wdoth(sW, hid2, 266 + u * 4 + w);
        o2[w * 5 + 0] = fmaf(wv, tm0, o2[w * 5 + 0]);
        o2[w * 5 + 1] = fmaf(wv, tm1, o2[w * 5 + 1]);
        o2[w * 5 + 2] = fmaf(wv, tm2, o2[w * 5 + 2]);
        o2[w * 5 + 3] = fmaf(wv, tm3, o2[w * 5 + 3]);
        o2[w * 5 + 4] = fmaf(wv, tm4, o2[w * 5 + 4]);
      }
    }
    // ---- P13 (l2 x Y0 -> l2), wa=278 ----
#pragma unroll
    for (int u = 0; u < 4; ++u) {
      float tm[5];
#pragma unroll
      for (int k = 0; k < 5; ++k) tm[k] = PS13 * xs[28 + u * 5 + k];
#pragma unroll
      for (int w = 0; w < 4; ++w) {
        float wv = wdoth(sW, hid2, 278 + u * 4 + w);
#pragma unroll
        for (int k = 0; k < 5; ++k) o2[w * 5 + k] = fmaf(wv, tm[k], o2[w * 5 + k]);
      }
    }
    // ---- P16 (l2 x Y2 -> l1e), C221 (antisym), wa=346 ----
#pragma unroll
    for (int u = 0; u < 4; ++u) {
      float Xa0 = xs[28 + u * 5 + 0], Xa1 = xs[28 + u * 5 + 1], Xa2 = xs[28 + u * 5 + 2];
      float Xa3 = xs[28 + u * 5 + 3], Xa4 = xs[28 + u * 5 + 4];
      float t0 = PS16 * (G122f * (Xa1 * Z2[4] - Xa4 * Z2[1]) + H122f * (Xa1 * Z2[2] - Xa2 * Z2[1]));
      float t1 = PS16 * (G122f * (-Xa0 * Z2[1] + Xa3 * Z2[4]) - H122f * Xa3 * Z2[2]);
      float t2 = PS16 * (G122f * Xa3 * Z2[1] - F122f * Xa0 * Z2[4]);
#pragma unroll
      for (int w = 0; w < 3; ++w) {
        float wv = wdoth(sW, hid2, 346 + u * 3 + w);
        oe[w * 3 + 0] = fmaf(wv, t0, oe[w * 3 + 0]);
        oe[w * 3 + 1] = fmaf(wv, t1, oe[w * 3 + 1]);
        oe[w * 3 + 2] = fmaf(wv, t2, oe[w * 3 + 2]);
      }
    }
    // ---- P17 (l2 x Y2 -> l2), C222 (Gaunt), wa=358 ----
#pragma unroll
    for (int u = 0; u < 4; ++u) {
      float Xa0 = xs[28 + u * 5 + 0], Xa1 = xs[28 + u * 5 + 1], Xa2 = xs[28 + u * 5 + 2];
      float Xa3 = xs[28 + u * 5 + 3], Xa4 = xs[28 + u * 5 + 4];
      float tm[5];
      tm[0] = PS17 * (-2.f * P222f * Xa0 * Z2[2] + SP222f * Xa3 * Z2[1]);
      tm[1] = PS17 * (P222f * (Xa1 * Z2[2] + Xa2 * Z2[1]) + SP222f * (-Xa1 * Z2[4] - Xa4 * Z2[1]));
      tm[2] = PS17 * (P222f * Xa1 * Z2[1] + 2.f * P222f * (Xa2 * Z2[2] - Xa4 * Z2[4]));
      tm[3] = PS17 * (P222f * Xa3 * Z2[2] + SP222f * (Xa3 * Z2[4] + Xa0 * Z2[1]));
      tm[4] = PS17 * (SP222f * (-Xa1 * Z2[1]) - 2.f * P222f * (Xa2 * Z2[4] + Xa4 * Z2[2]));
#pragma unroll
      for (int w = 0; w < 4; ++w) {
        float wv = wdoth(sW, hid2, 358 + u * 4 + w);
#pragma unroll
        for (int k = 0; k < 5; ++k) o2[w * 5 + k] = fmaf(wv, tm[k], o2[w * 5 + k]);
      }
    }

    // store o[19:48]
    mp[19] = oe[0];
    float pk[28];
#pragma unroll
    for (int j = 0; j < 8; ++j) pk[j] = oe[1 + j];
#pragma unroll
    for (int j = 0; j < 20; ++j) pk[8 + j] = o2[j];
#pragma unroll
    for (int q = 0; q < 7; ++q) ((float4*)(mp + 20))[q] = ((float4*)pk)[q];
  }
}

// =================== CSR gather: one wave per node, lane = feature; contiguous rows ===================
__global__ void k_agg(const int* __restrict__ off, const float* __restrict__ MSG,
                      float* __restrict__ AGG) {
  int gt = blockIdx.x * blockDim.x + threadIdx.x;
  int wid = gt >> 6;          // node
  int lane = threadIdx.x & 63;
  if (wid >= BN) return;
  int a = off[wid], bnd = off[wid + 1];
  if (lane < 48) {
    float s = 0.f;
    for (int k = a; k < bnd; ++k) s += MSG[(size_t)k * 48 + lane];
    AGG[(size_t)wid * 48 + lane] = s;
  }
}

// =================== self-term + norm_act ===================
__global__ void k_post(const float* __restrict__ AGG, const float* __restrict__ hin,
                       const float* __restrict__ w0, const float* __restrict__ b0,
                       const float* __restrict__ w1o, const float* __restrict__ w1e,
                       const float* __restrict__ w2e, const float* __restrict__ mask_n,
                       float* __restrict__ hout) {
  int t = blockIdx.x * blockDim.x + threadIdx.x;
  if (t >= BN) return;
  float h[48], li[48], s[48];
  const float4* hp = (const float4*)(hin + (size_t)t * 48);
#pragma unroll
  for (int q = 0; q < 12; ++q) ((float4*)h)[q] = hp[q];
  lin48(h, w0, b0, w1o, w1e, w2e, li);
  const float4* gp = (const float4*)(AGG + (size_t)t * 48);
#pragma unroll
  for (int q = 0; q < 12; ++q) ((float4*)s)[q] = gp[q];
#pragma unroll
  for (int j = 0; j < 48; ++j) s[j] += li[j];
  float mk = mask_n[t];
  float r[48];
#pragma unroll
  for (int j = 0; j < 10; ++j) {
    float v = s[j];
    r[j] = v * sigm(sqrtf(v * v + 1e-12f)) * mk;
  }
#pragma unroll
  for (int u = 0; u < 3; ++u) {
    float n1 = 0.f, n2 = 0.f;
#pragma unroll
    for (int m = 0; m < 3; ++m) {
      n1 = fmaf(s[10 + u * 3 + m], s[10 + u * 3 + m], n1);
      n2 = fmaf(s[19 + u * 3 + m], s[19 + u * 3 + m], n2);
    }
    float f1 = sigm(sqrtf(n1 + 1e-12f)) * mk;
    float f2 = sigm(sqrtf(n2 + 1e-12f)) * mk;
#pragma unroll
    for (int m = 0; m < 3; ++m) {
      r[10 + u * 3 + m] = s[10 + u * 3 + m] * f1;
      r[19 + u * 3 + m] = s[19 + u * 3 + m] * f2;
    }
  }
#pragma unroll
  for (int u = 0; u < 4; ++u) {
    float n3 = 0.f;
#pragma unroll
    for (int m = 0; m < 5; ++m) n3 = fmaf(s[28 + u * 5 + m], s[28 + u * 5 + m], n3);
    float f3 = sigm(sqrtf(n3 + 1e-12f)) * mk;
#pragma unroll
    for (int m = 0; m < 5; ++m) r[28 + u * 5 + m] = s[28 + u * 5 + m] * f3;
  }
  float4* op = (float4*)(hout + (size_t)t * 48);
#pragma unroll
  for (int q = 0; q < 12; ++q) op[q] = ((float4*)r)[q];
}

// =================== readout ===================
__global__ void k_out(const float* __restrict__ h, const int* __restrict__ centers,
                      const float* __restrict__ sw0, const float* __restrict__ sb0,
                      const float* __restrict__ sw2, float* __restrict__ out) {
  int b = threadIdx.x;
  if (b >= Bb) return;
  int c = centers[b];
  const float* hc = h + ((size_t)(b * Nn + c)) * 48;
  float acc = 0.f;
#pragma unroll
  for (int u = 0; u < 10; ++u) acc = fmaf(hc[u], sw0[u], acc);
  float tr = acc * RS10f + sb0[0];
  float s2[5];
#pragma unroll
  for (int m = 0; m < 5; ++m) {
    float a = 0.f;
#pragma unroll
    for (int u = 0; u < 4; ++u) a = fmaf(hc[28 + u * 5 + m], sw2[u], a);
    s2[m] = a * 0.5f;
  }
  float a0 = s2[0], a2c = s2[1], a2s = s2[2], a1c = s2[3], a1s = s2[4];
  const float is6 = 0.4082482904638630f;
  const float is2 = 0.7071067811865476f;
  const float i3 = 0.3333333333333333f;
  out[b * 6 + 0] = -a0 * is6 + a2c * is2 + tr * i3;
  out[b * 6 + 1] = a2s;
  out[b * 6 + 2] = a1c;
  out[b * 6 + 3] = -a0 * is6 - a2c * is2 + tr * i3;
  out[b * 6 + 4] = a1s;
  out[b * 6 + 5] = 2.f * a0 * is6 + tr * i3;
}

// =================== host launch ===================
extern "C" void kernel_launch(void* const* d_in, const int* in_sizes, int n_in,
                              void* d_out, int out_size, void* d_ws, size_t ws_size,
                              hipStream_t stream) {
  const float* x_nodes = (const float*)d_in[0];
  const float* e_attr2 = (const float*)d_in[1];
  const float* mask_n  = (const float*)d_in[2];
  const float* mask_e  = (const float*)d_in[3];
  const float* enc_w0  = (const float*)d_in[4];
  const float* enc_b0  = (const float*)d_in[5];
  const float* enc_w1e = (const float*)d_in[6];
  const float* enc_w2e = (const float*)d_in[7];
  const float* li_w0   = (const float*)d_in[8];
  const float* li_b0   = (const float*)d_in[9];
  const float* li_w1o  = (const float*)d_in[10];
  const float* li_w1e  = (const float*)d_in[11];
  const float* li_w2e  = (const float*)d_in[12];
  const float* rad_w1  = (const float*)d_in[13];
  const float* rad_w2  = (const float*)d_in[14];
  const float* lr_w0   = (const float*)d_in[15];
  const float* lr_b0   = (const float*)d_in[16];
  const float* lr_w1o  = (const float*)d_in[17];
  const float* lr_w1e  = (const float*)d_in[18];
  const float* lr_w2e  = (const float*)d_in[19];
  const float* sym_w0  = (const float*)d_in[20];
  const float* sym_b0  = (const float*)d_in[21];
  const float* sym_w2e = (const float*)d_in[22];
  const int* e_src = (const int*)d_in[23];
  const int* e_dst = (const int*)d_in[24];
  const int* centers = (const int*)d_in[25];
  float* out = (float*)d_out;

  float* ws  = (float*)d_ws;
  float* hA  = ws;
  float* hB  = hA + (size_t)BN * 48;
  float* HIN = hB + (size_t)BN * 48;
  float* AGG = HIN + (size_t)BN * 48;
  float* MSG = AGG + (size_t)BN * 48;                 // BE*48 f32 = 50.3 MB
  uint32_t* R2T16 = (uint32_t*)(MSG + (size_t)BE * 48);
  int* deg    = (int*)(R2T16 + 2 * NW * 16);
  int* off    = deg + BN;        // BN+1
  int* cursor = off + BN + 1;
  int* bsum   = cursor + BN;     // 128
  int* boff   = bsum + 128;      // 128
  int* epos   = boff + 128;      // BE

  k_tr<<<3, 256, 0, stream>>>(rad_w2, R2T16);
  k_enc<<<BN / 256, 256, 0, stream>>>(x_nodes, mask_n, enc_w0, enc_b0, enc_w1e, enc_w2e, hA);

  // CSR of e_dst (constant across layers)
  (void)hipMemsetAsync(deg, 0, (size_t)BN * sizeof(int), stream);
  k_count<<<BE / 256, 256, 0, stream>>>(e_dst, deg);
  k_scan_block<<<BN / 256, 256, 0, stream>>>(deg, off, bsum);
  k_scan_bsum<<<1, 128, 0, stream>>>(bsum, boff);
  k_scan_add<<<BN / 256, 256, 0, stream>>>(boff, off, cursor);
  k_fill<<<BE / 256, 256, 0, stream>>>(e_dst, cursor, epos);

  float* hcur = hA;
  float* hnext = hB;
  for (int l = 0; l < 2; ++l) {
    k_lin<<<BN / 256, 256, 0, stream>>>(hcur, li_w0 + l * 100, li_b0 + l * 10,
                                        li_w1o + l * 9, li_w1e + l * 9, li_w2e + l * 16, HIN);
    k_msg<<<BE / 256, 256, 0, stream>>>(HIN, e_attr2, mask_e, rad_w1 + l * 32,
                                        R2T16 + (size_t)l * NW * 16, e_src, epos, MSG);
    k_agg<<<(BN * 64) / 256, 256, 0, stream>>>(off, MSG, AGG);
    k_post<<<BN / 256, 256, 0, stream>>>(AGG, hcur, lr_w0 + l * 100, lr_b0 + l * 10,
                                         lr_w1o + l * 9, lr_w1e + l * 9, lr_w2e + l * 16,
                                         mask_n, hnext);
    float* tswap = hcur; hcur = hnext; hnext = tswap;
  }
  k_out<<<1, 64, 0, stream>>>(hcur, centers, sym_w0, sym_b0, sym_w2e, out);
}

// Round 10
// 436.504 us; speedup vs baseline: 3.0808x; 2.4731x over previous
//
#include <hip/hip_runtime.h>
#include <hip/hip_fp16.h>
#include <math.h>
#include <stdint.h>

// =================== problem constants ===================
constexpr int Bb = 4;
constexpr int Nn = 8192;
constexpr int Ee = 65536;
constexpr int BN = Bb * Nn;   // 32768 nodes
constexpr int BE = Bb * Ee;   // 262144 edges
constexpr int NW = 374;       // radial weight columns
constexpr int NWU = NW * 16;  // u32 (f16x2) elements in the table

// w3j tie-break signs — VERIFIED round 1 (absmax 0.0)
#define S111 (+1.0f)
#define S122 (-1.0f)
#define S221 (-1.0f)
#define S222 (-1.0f)

#define SQ3f   1.7320508075688772f
#define SQ15f  3.872983346207417f
#define HSQ5f  1.118033988749895f
#define HSQ15f 1.9364916731037085f
#define RS10f  0.31622776601683794f
#define RS3f   0.5773502691896258f
#define RS32f  0.17677669529663687f
#define K1f    0.5773502691896258f
#define K2f    0.4472135954999579f
#define K6f    0.40824829046386296f
#define A0f    0.24253562503633297f
#define A1f    0.3612106650782119f
#define A2f    0.4803844614152614f
#define A3f    0.4564354645876384f
#define A112f  0.31622776601683794f
#define B112f  0.3651483716701107f
#define C112f  0.18257418583505536f
#define G122f  0.18257418583505536f
#define H122f  0.31622776601683794f
#define F122f  0.3651483716701107f
#define P222f  0.11952286093343936f
#define SP222f 0.20701966780270626f

#define PS1  (A0f*RS32f)
#define PS2  (A1f*RS32f*K1f)
#define PS3  (A3f*RS32f*K2f)
#define PS4  (A1f*RS32f*K1f)
#define PS5  (A0f*RS32f*K1f)
#define PS6  (A2f*RS32f*K6f*S111)
#define PS7  (A3f*RS32f)
#define PS8  (A1f*RS32f)
#define PS9  (A2f*RS32f*K1f)
#define PS10 (A1f*RS32f*K6f*S111)
#define PS11 (A2f*RS32f)
#define PS12 (A3f*RS32f*S122)
#define PS13 (A3f*RS32f*K2f)
#define PS14 (A1f*RS32f)
#define PS15 (A0f*RS32f*K2f)
#define PS16 (A2f*RS32f*S221)
#define PS17 (A3f*RS32f*S222)

typedef _Float16 h2v __attribute__((ext_vector_type(2)));   // fdot2 operand type
typedef __fp16   p2v __attribute__((ext_vector_type(2)));   // cvt_pkrtz result type
union H2U { uint32_t u; h2v h; p2v p; };

__device__ __forceinline__ float sigm(float z) { return 1.f / (1.f + __expf(-z)); }

// dot over 32 radial-hidden units; LDS broadcast reads; 2 accumulators halve the dep chain
__device__ __forceinline__ float wdoth(const uint32_t* sW,
                                       const uint32_t hid2[16], int col) {
  float a0 = 0.f, a1 = 0.f;
  const uint32_t* p = sW + col * 16;
#pragma unroll
  for (int q = 0; q < 16; q += 2) {
    H2U x0; x0.u = hid2[q];     H2U y0; y0.u = p[q];
    H2U x1; x1.u = hid2[q + 1]; H2U y1; y1.u = p[q + 1];
#if defined(__has_builtin) && __has_builtin(__builtin_amdgcn_fdot2)
    a0 = __builtin_amdgcn_fdot2(x0.h, y0.h, a0, false);
    a1 = __builtin_amdgcn_fdot2(x1.h, y1.h, a1, false);
#else
    a0 = fmaf((float)x0.h[0], (float)y0.h[0], a0);
    a0 = fmaf((float)x0.h[1], (float)y0.h[1], a0);
    a1 = fmaf((float)x1.h[0], (float)y1.h[0], a1);
    a1 = fmaf((float)x1.h[1], (float)y1.h[1], a1);
#endif
  }
  return a0 + a1;
}

// =================== transpose+convert rad_w2 -> f16 packed [L][374][16] ===================
__global__ void k_tr(const float* __restrict__ R2all, uint32_t* __restrict__ T) {
  int t = blockIdx.x * blockDim.x + threadIdx.x;
  if (t >= 2 * NW) return;
  int l = t / NW, c = t - l * NW;
  const float* src = R2all + (size_t)l * 32 * NW + c;
  uint32_t* dst = T + (size_t)t * 16;
#pragma unroll
  for (int p = 0; p < 16; ++p) {
    H2U u;
    u.p = __builtin_amdgcn_cvt_pkrtz(src[(size_t)(2 * p) * NW], src[(size_t)(2 * p + 1) * NW]);
    dst[p] = u.u;
  }
}

// =================== encoder ===================
__global__ void k_enc(const float* __restrict__ xn, const float* __restrict__ mask_n,
                      const float* __restrict__ ew0, const float* __restrict__ eb0,
                      const float* __restrict__ ew1e, const float* __restrict__ ew2e,
                      float* __restrict__ h) {
  int t = blockIdx.x * blockDim.x + threadIdx.x;
  if (t >= BN) return;
  const float* x9 = xn + (size_t)t * 9;
  float U00 = x9[0], U01 = x9[1], U02 = x9[2];
  float U10 = x9[3], U11 = x9[4], U12 = x9[5];
  float U20 = x9[6], U21 = x9[7], U22 = x9[8];
  float tr = U00 + U11 + U22;
  float a[5];
  a[0] = (2.f * U22 - U00 - U11) * 0.4082482904638630f;
  a[1] = (U00 - U11) * 0.7071067811865476f;
  a[2] = 0.7071067811865476f * (U01 + U10);
  a[3] = 0.7071067811865476f * (U02 + U20);
  a[4] = 0.7071067811865476f * (U12 + U21);
  float om[3];
  om[0] = 0.5f * (U12 - U21);
  om[1] = 0.5f * (U20 - U02);
  om[2] = 0.5f * (U01 - U10);
  float mk = mask_n[t];
  float o[48];
#pragma unroll
  for (int j = 0; j < 10; ++j) o[j] = (tr * ew0[j] + eb0[j]) * mk;
#pragma unroll
  for (int j = 10; j < 19; ++j) o[j] = 0.f;
#pragma unroll
  for (int w = 0; w < 3; ++w)
#pragma unroll
    for (int mm = 0; mm < 3; ++mm) o[19 + w * 3 + mm] = om[mm] * ew1e[w] * mk;
#pragma unroll
  for (int w = 0; w < 4; ++w)
#pragma unroll
    for (int mm = 0; mm < 5; ++mm) o[28 + w * 5 + mm] = a[mm] * ew2e[w] * mk;
  float4* hp = (float4*)(h + (size_t)t * 48);
#pragma unroll
  for (int q = 0; q < 12; ++q) hp[q] = ((float4*)o)[q];
}

// =================== per-channel linear (lin_hid) ===================
__device__ __forceinline__ void lin48(const float h[48], const float* __restrict__ w0,
                                      const float* __restrict__ b0, const float* __restrict__ w1o,
                                      const float* __restrict__ w1e, const float* __restrict__ w2e,
                                      float o[48]) {
#pragma unroll
  for (int j = 0; j < 10; ++j) {
    float s = 0.f;
#pragma unroll
    for (int u = 0; u < 10; ++u) s = fmaf(h[u], w0[u * 10 + j], s);
    o[j] = s * RS10f + b0[j];
  }
#pragma unroll
  for (int w = 0; w < 3; ++w) {
#pragma unroll
    for (int m = 0; m < 3; ++m) {
      float s1 = 0.f, s2 = 0.f;
#pragma unroll
      for (int u = 0; u < 3; ++u) {
        s1 = fmaf(h[10 + u * 3 + m], w1o[u * 3 + w], s1);
        s2 = fmaf(h[19 + u * 3 + m], w1e[u * 3 + w], s2);
      }
      o[10 + w * 3 + m] = s1 * RS3f;
      o[19 + w * 3 + m] = s2 * RS3f;
    }
  }
#pragma unroll
  for (int w = 0; w < 4; ++w) {
#pragma unroll
    for (int m = 0; m < 5; ++m) {
      float s = 0.f;
#pragma unroll
      for (int u = 0; u < 4; ++u) s = fmaf(h[28 + u * 5 + m], w2e[u * 4 + w], s);
      o[28 + w * 5 + m] = s * 0.5f;
    }
  }
}

__global__ void k_lin(const float* __restrict__ hin, const float* __restrict__ w0,
                      const float* __restrict__ b0, const float* __restrict__ w1o,
                      const float* __restrict__ w1e, const float* __restrict__ w2e,
                      float* __restrict__ hout) {
  int t = blockIdx.x * blockDim.x + threadIdx.x;
  if (t >= BN) return;
  float h[48], o[48];
  const float4* hp = (const float4*)(hin + (size_t)t * 48);
#pragma unroll
  for (int q = 0; q < 12; ++q) ((float4*)h)[q] = hp[q];
  lin48(h, w0, b0, w1o, w1e, w2e, o);
  float4* op = (float4*)(hout + (size_t)t * 48);
#pragma unroll
  for (int q = 0; q < 12; ++q) op[q] = ((float4*)o)[q];
}

// =================== CSR build (e_dst is constant across layers) ===================
__global__ void k_count(const int* __restrict__ edst, int* __restrict__ deg) {
  int t = blockIdx.x * blockDim.x + threadIdx.x;
  if (t >= BE) return;
  int b = t >> 16;
  atomicAdd(&deg[edst[t] + (b << 13)], 1);
}

__global__ void k_scan_block(const int* __restrict__ deg, int* __restrict__ off,
                             int* __restrict__ bsum) {
  __shared__ int sh[256];
  int i = threadIdx.x, g = blockIdx.x * 256 + i;
  int v = deg[g];
  sh[i] = v;
  __syncthreads();
  for (int d = 1; d < 256; d <<= 1) {
    int tv = (i >= d) ? sh[i - d] : 0;
    __syncthreads();
    sh[i] += tv;
    __syncthreads();
  }
  off[g] = sh[i] - v;  // exclusive within block
  if (i == 255) bsum[blockIdx.x] = sh[i];
}

__global__ void k_scan_bsum(int* __restrict__ bsum, int* __restrict__ boff) {
  __shared__ int sh[128];
  int i = threadIdx.x;
  int v = bsum[i];
  sh[i] = v;
  __syncthreads();
  for (int d = 1; d < 128; d <<= 1) {
    int tv = (i >= d) ? sh[i - d] : 0;
    __syncthreads();
    sh[i] += tv;
    __syncthreads();
  }
  boff[i] = sh[i] - v;  // exclusive
}

__global__ void k_scan_add(const int* __restrict__ boff, int* __restrict__ off,
                           int* __restrict__ cursor) {
  int g = blockIdx.x * 256 + threadIdx.x;
  int v = off[g] + boff[blockIdx.x];
  off[g] = v;
  cursor[g] = v;
  if (g == 0) off[BN] = BE;
}

// epos[t] = CSR slot of edge t -> k_msg stores in CSR order, k_agg reads contiguous
__global__ void k_fill(const int* __restrict__ edst, int* __restrict__ cursor,
                       int* __restrict__ epos) {
  int t = blockIdx.x * blockDim.x + threadIdx.x;
  if (t >= BE) return;
  int b = t >> 16;
  int d = edst[t] + (b << 13);
  int pos = atomicAdd(&cursor[d], 1);
  epos[t] = pos;
}

// =================== message kernel ===================
// Round 9 post-mortem: any VGPR cap of 128 makes the allocator fall to 64 +
// catastrophic spill (1.3 GB scratch traffic). Round 5 proved cap 256 fits
// (VGPR=256, no spill) but launch_bounds(256,1) allowed only ~1 wave/SIMD.
// Now: __launch_bounds__(256,2) -> cap 256 (no cliff possible), >=2 waves/SIMD
// guaranteed. True live set shrunk by reloading xs slices per path-group
// (HIN is 6MB, L2/L3-resident) with sched_barrier fences so the scheduler
// can't hoist all loads and re-inflate pressure -> chance of <=128 (4 waves).
__global__ __launch_bounds__(256, 2) void k_msg(
    const float* __restrict__ HIN, const float* __restrict__ e_attr2,
    const float* __restrict__ mask_e, const float* __restrict__ rw1,
    const uint32_t* __restrict__ W16, const int* __restrict__ esrc,
    const int* __restrict__ epos, float* __restrict__ MSG) {
  __shared__ __align__(16) uint32_t sW[NWU];   // 23936 B
  int tid = threadIdx.x;
  {
    const uint4* src4 = (const uint4*)W16;
    uint4* dst4 = (uint4*)sW;
#pragma unroll
    for (int i = 0; i < 6; ++i) {
      int idx = tid + i * 256;
      if (idx < NWU / 4) dst4[idx] = src4[idx];
    }
  }
  __syncthreads();

  int t = blockIdx.x * blockDim.x + tid;
  if (t >= BE) return;
  int b = t >> 16;
  int srow = esrc[t] + (b << 13);

  float mke = mask_e[t];
  float ey = e_attr2[2 * t] * mke;
  float ez = e_attr2[2 * t + 1] * mke;
  float rn = sqrtf(ey * ey + ez * ez) + 1e-8f;
  float yy = ey / rn, zz = ez / rn;
  const float Z1[3] = {0.f, SQ3f * yy, SQ3f * zz};
  const float Z2[5] = {0.f, SQ15f * yy * zz, HSQ5f * (2.f * zz * zz - yy * yy),
                       0.f, -HSQ15f * yy * yy};
  uint32_t hid2[16];
#pragma unroll
  for (int q = 0; q < 16; ++q) {
    float z0 = rn * rw1[2 * q];
    float z1 = rn * rw1[2 * q + 1];
    H2U u;
    u.p = __builtin_amdgcn_cvt_pkrtz(z0 * sigm(z0), z1 * sigm(z1));
    hid2[q] = u.u;
  }
  const float4* xr = (const float4*)(HIN + (size_t)srow * 48);
  float* mp = MSG + (size_t)epos[t] * 48;

  // ========== PHASE 1: o[0:19] = l0 + l1o ==========
  {
    float o[19];
#pragma unroll
    for (int j = 0; j < 19; ++j) o[j] = 0.f;

    // --- group A: xs[0:10) -> P1, P2 ---
    float ga[12];
    ((float4*)ga)[0] = xr[0]; ((float4*)ga)[1] = xr[1]; ((float4*)ga)[2] = xr[2];
    // P1 (l0 x Y0 -> l0), wa=0
#pragma unroll
    for (int u = 0; u < 10; ++u) {
      float xu = PS1 * ga[u];
#pragma unroll
      for (int w = 0; w < 10; ++w) o[w] = fmaf(wdoth(sW, hid2, u * 10 + w), xu, o[w]);
    }
    // P2 (l0 x Y1 -> l1o), wa=100 (t0 = 0)
#pragma unroll
    for (int u = 0; u < 10; ++u) {
      float xu = PS2 * ga[u];
      float t1 = xu * Z1[1], t2 = xu * Z1[2];
#pragma unroll
      for (int w = 0; w < 3; ++w) {
        float wv = wdoth(sW, hid2, 100 + u * 3 + w);
        o[10 + w * 3 + 1] = fmaf(wv, t1, o[10 + w * 3 + 1]);
        o[10 + w * 3 + 2] = fmaf(wv, t2, o[10 + w * 3 + 2]);
      }
    }
    __builtin_amdgcn_sched_barrier(0);

    // --- group B: xs[10:19) -> P4, P5, P8 ---  gb[i]=xs[8+i]
    float gb[12];
    ((float4*)gb)[0] = xr[2]; ((float4*)gb)[1] = xr[3]; ((float4*)gb)[2] = xr[4];
    // P4 (l1o x Y0 -> l1o), wa=170
#pragma unroll
    for (int u = 0; u < 3; ++u) {
      float t0 = PS4 * gb[2 + u * 3 + 0], t1 = PS4 * gb[2 + u * 3 + 1], t2 = PS4 * gb[2 + u * 3 + 2];
#pragma unroll
      for (int w = 0; w < 3; ++w) {
        float wv = wdoth(sW, hid2, 170 + u * 3 + w);
        o[10 + w * 3 + 0] = fmaf(wv, t0, o[10 + w * 3 + 0]);
        o[10 + w * 3 + 1] = fmaf(wv, t1, o[10 + w * 3 + 1]);
        o[10 + w * 3 + 2] = fmaf(wv, t2, o[10 + w * 3 + 2]);
      }
    }
    // P5 (l1o x Y1 -> l0), wa=179
#pragma unroll
    for (int u = 0; u < 3; ++u) {
      float s = PS5 * (gb[2 + u * 3 + 1] * Z1[1] + gb[2 + u * 3 + 2] * Z1[2]);
#pragma unroll
      for (int w = 0; w < 10; ++w) o[w] = fmaf(wdoth(sW, hid2, 179 + u * 10 + w), s, o[w]);
    }
    // P8 (l1o x Y2 -> l1o), C121, wa=230
#pragma unroll
    for (int u = 0; u < 3; ++u) {
      float X0 = gb[2 + u * 3 + 0], X1 = gb[2 + u * 3 + 1], X2 = gb[2 + u * 3 + 2];
      float t0 = PS8 * (A112f * X0 * Z2[4] - C112f * X0 * Z2[2]);
      float t1 = PS8 * (A112f * (X2 * Z2[1] - X1 * Z2[4]) - C112f * X1 * Z2[2]);
      float t2 = PS8 * (A112f * X1 * Z2[1] + B112f * X2 * Z2[2]);
#pragma unroll
      for (int w = 0; w < 3; ++w) {
        float wv = wdoth(sW, hid2, 230 + u * 3 + w);
        o[10 + w * 3 + 0] = fmaf(wv, t0, o[10 + w * 3 + 0]);
        o[10 + w * 3 + 1] = fmaf(wv, t1, o[10 + w * 3 + 1]);
        o[10 + w * 3 + 2] = fmaf(wv, t2, o[10 + w * 3 + 2]);
      }
    }
    __builtin_amdgcn_sched_barrier(0);

    // --- group C: xs[19:28) -> P10 ---  gc[i]=xs[16+i]
    float gc[12];
    ((float4*)gc)[0] = xr[4]; ((float4*)gc)[1] = xr[5]; ((float4*)gc)[2] = xr[6];
    // P10 (l1e x Y1 -> l1o), eps, wa=248
#pragma unroll
    for (int u = 0; u < 3; ++u) {
      float X0 = gc[3 + u * 3 + 0], X1 = gc[3 + u * 3 + 1], X2 = gc[3 + u * 3 + 2];
      float c0 = PS10 * (X1 * Z1[2] - X2 * Z1[1]);
      float c1 = PS10 * (-X0 * Z1[2]);
      float c2 = PS10 * (X0 * Z1[1]);
#pragma unroll
      for (int w = 0; w < 3; ++w) {
        float wv = wdoth(sW, hid2, 248 + u * 3 + w);
        o[10 + w * 3 + 0] = fmaf(wv, c0, o[10 + w * 3 + 0]);
        o[10 + w * 3 + 1] = fmaf(wv, c1, o[10 + w * 3 + 1]);
        o[10 + w * 3 + 2] = fmaf(wv, c2, o[10 + w * 3 + 2]);
      }
    }
    __builtin_amdgcn_sched_barrier(0);

    // --- group D: xs[28:48) -> P14, P15 ---  gd[i]=xs[28+i]
    float gd[20];
#pragma unroll
    for (int q = 0; q < 5; ++q) ((float4*)gd)[q] = xr[7 + q];
    // P14 (l2 x Y1 -> l1o), C211, wa=294
#pragma unroll
    for (int u = 0; u < 4; ++u) {
      float Xa0 = gd[u * 5 + 0], Xa1 = gd[u * 5 + 1], Xa2 = gd[u * 5 + 2];
      float Xa3 = gd[u * 5 + 3], Xa4 = gd[u * 5 + 4];
      float t0 = PS14 * (A112f * (Z1[1] * Xa0 + Z1[2] * Xa3));
      float t1 = PS14 * (A112f * (Z1[2] * Xa1 - Z1[1] * Xa4) - C112f * Z1[1] * Xa2);
      float t2 = PS14 * (A112f * Z1[1] * Xa1 + B112f * Z1[2] * Xa2);
#pragma unroll
      for (int w = 0; w < 3; ++w) {
        float wv = wdoth(sW, hid2, 294 + u * 3 + w);
        o[10 + w * 3 + 0] = fmaf(wv, t0, o[10 + w * 3 + 0]);
        o[10 + w * 3 + 1] = fmaf(wv, t1, o[10 + w * 3 + 1]);
        o[10 + w * 3 + 2] = fmaf(wv, t2, o[10 + w * 3 + 2]);
      }
    }
    // P15 (l2 x Y2 -> l0), wa=306
#pragma unroll
    for (int u = 0; u < 4; ++u) {
      float s = PS15 * (gd[u * 5 + 1] * Z2[1] + gd[u * 5 + 2] * Z2[2] + gd[u * 5 + 4] * Z2[4]);
#pragma unroll
      for (int w = 0; w < 10; ++w) o[w] = fmaf(wdoth(sW, hid2, 306 + u * 10 + w), s, o[w]);
    }

    // store o[0:19]
#pragma unroll
    for (int q = 0; q < 4; ++q) ((float4*)mp)[q] = ((float4*)o)[q];
    mp[16] = o[16]; mp[17] = o[17]; mp[18] = o[18];
  }

  __builtin_amdgcn_sched_barrier(0);

  // ========== PHASE 2: o[19:48] = l1e + l2 ==========
  {
    float oe[9];
    float o2[20];
#pragma unroll
    for (int j = 0; j < 9; ++j) oe[j] = 0.f;
#pragma unroll
    for (int j = 0; j < 20; ++j) o2[j] = 0.f;

    // --- group A: xs[0:10) -> P3 ---
    float ga[12];
    ((float4*)ga)[0] = xr[0]; ((float4*)ga)[1] = xr[1]; ((float4*)ga)[2] = xr[2];
    // P3 (l0 x Y2 -> l2), wa=130
#pragma unroll
    for (int u = 0; u < 10; ++u) {
      float xu = PS3 * ga[u];
      float m1 = xu * Z2[1], m2 = xu * Z2[2], m4 = xu * Z2[4];
#pragma unroll
      for (int w = 0; w < 4; ++w) {
        float wv = wdoth(sW, hid2, 130 + u * 4 + w);
        o2[w * 5 + 1] = fmaf(wv, m1, o2[w * 5 + 1]);
        o2[w * 5 + 2] = fmaf(wv, m2, o2[w * 5 + 2]);
        o2[w * 5 + 4] = fmaf(wv, m4, o2[w * 5 + 4]);
      }
    }
    __builtin_amdgcn_sched_barrier(0);

    // --- group B: xs[10:19) -> P6, P7 ---
    float gb[12];
    ((float4*)gb)[0] = xr[2]; ((float4*)gb)[1] = xr[3]; ((float4*)gb)[2] = xr[4];
    // P6 (l1o x Y1 -> l1e), eps, wa=209
#pragma unroll
    for (int u = 0; u < 3; ++u) {
      float X0 = gb[2 + u * 3 + 0], X1 = gb[2 + u * 3 + 1], X2 = gb[2 + u * 3 + 2];
      float c0 = PS6 * (X1 * Z1[2] - X2 * Z1[1]);
      float c1 = PS6 * (-X0 * Z1[2]);
      float c2 = PS6 * (X0 * Z1[1]);
#pragma unroll
      for (int w = 0; w < 3; ++w) {
        float wv = wdoth(sW, hid2, 209 + u * 3 + w);
        oe[w * 3 + 0] = fmaf(wv, c0, oe[w * 3 + 0]);
        oe[w * 3 + 1] = fmaf(wv, c1, oe[w * 3 + 1]);
        oe[w * 3 + 2] = fmaf(wv, c2, oe[w * 3 + 2]);
      }
    }
    // P7 (l1o x Y1 -> l2), C112, wa=218 (tm0 = A112f*X0*Z1[1])
#pragma unroll
    for (int u = 0; u < 3; ++u) {
      float X0 = gb[2 + u * 3 + 0], X1 = gb[2 + u * 3 + 1], X2 = gb[2 + u * 3 + 2];
      float tm0 = PS7 * (A112f * X0 * Z1[1]);
      float tm1 = PS7 * (A112f * (X1 * Z1[2] + X2 * Z1[1]));
      float tm2 = PS7 * (B112f * X2 * Z1[2] - C112f * X1 * Z1[1]);
      float tm3 = PS7 * (A112f * X0 * Z1[2]);
      float tm4 = PS7 * (-A112f * X1 * Z1[1]);
#pragma unroll
      for (int w = 0; w < 4; ++w) {
        float wv = wdoth(sW, hid2, 218 + u * 4 + w);
        o2[w * 5 + 0] = fmaf(wv, tm0, o2[w * 5 + 0]);
        o2[w * 5 + 1] = fmaf(wv, tm1, o2[w * 5 + 1]);
        o2[w * 5 + 2] = fmaf(wv, tm2, o2[w * 5 + 2]);
        o2[w * 5 + 3] = fmaf(wv, tm3, o2[w * 5 + 3]);
        o2[w * 5 + 4] = fmaf(wv, tm4, o2[w * 5 + 4]);
      }
    }
    __builtin_amdgcn_sched_barrier(0);

    // --- group C: xs[19:28) -> P9, P11, P12 ---
    float gc[12];
    ((float4*)gc)[0] = xr[4]; ((float4*)gc)[1] = xr[5]; ((float4*)gc)[2] = xr[6];
    // P9 (l1e x Y0 -> l1e), wa=239
#pragma unroll
    for (int u = 0; u < 3; ++u) {
      float t0 = PS9 * gc[3 + u * 3 + 0], t1 = PS9 * gc[3 + u * 3 + 1], t2 = PS9 * gc[3 + u * 3 + 2];
#pragma unroll
      for (int w = 0; w < 3; ++w) {
        float wv = wdoth(sW, hid2, 239 + u * 3 + w);
        oe[w * 3 + 0] = fmaf(wv, t0, oe[w * 3 + 0]);
        oe[w * 3 + 1] = fmaf(wv, t1, oe[w * 3 + 1]);
        oe[w * 3 + 2] = fmaf(wv, t2, oe[w * 3 + 2]);
      }
    }
    // P11 (l1e x Y2 -> l1e), C121, wa=257
#pragma unroll
    for (int u = 0; u < 3; ++u) {
      float X0 = gc[3 + u * 3 + 0], X1 = gc[3 + u * 3 + 1], X2 = gc[3 + u * 3 + 2];
      float t0 = PS11 * (A112f * X0 * Z2[4] - C112f * X0 * Z2[2]);
      float t1 = PS11 * (A112f * (X2 * Z2[1] - X1 * Z2[4]) - C112f * X1 * Z2[2]);
      float t2 = PS11 * (A112f * X1 * Z2[1] + B112f * X2 * Z2[2]);
#pragma unroll
      for (int w = 0; w < 3; ++w) {
        float wv = wdoth(sW, hid2, 257 + u * 3 + w);
        oe[w * 3 + 0] = fmaf(wv, t0, oe[w * 3 + 0]);
        oe[w * 3 + 1] = fmaf(wv, t1, oe[w * 3 + 1]);
        oe[w * 3 + 2] = fmaf(wv, t2, oe[w * 3 + 2]);
      }
    }
    // P12 (l1e x Y2 -> l2), C122 (antisym), wa=266
#pragma unroll
    for (int u = 0; u < 3; ++u) {
      float X0 = gc[3 + u * 3 + 0], X1 = gc[3 + u * 3 + 1], X2 = gc[3 + u * 3 + 2];
      float tm0 = PS12 * (G122f * X1 * Z2[1] + F122f * X2 * Z2[4]);
      float tm1 = PS12 * (-H122f * X0 * Z2[2] - G122f * X0 * Z2[4]);
      float tm2 = PS12 * (H122f * X0 * Z2[1]);
      float tm3 = PS12 * (H122f * X1 * Z2[2] - G122f * X1 * Z2[4] - G122f * X2 * Z2[1]);
      float tm4 = PS12 * (G122f * X0 * Z2[1]);
#pragma unroll
      for (int w = 0; w < 4; ++w) {
        float wv = wdoth(sW, hid2, 266 + u * 4 + w);
        o2[w * 5 + 0] = fmaf(wv, tm0, o2[w * 5 + 0]);
        o2[w * 5 + 1] = fmaf(wv, tm1, o2[w * 5 + 1]);
        o2[w * 5 + 2] = fmaf(wv, tm2, o2[w * 5 + 2]);
        o2[w * 5 + 3] = fmaf(wv, tm3, o2[w * 5 + 3]);
        o2[w * 5 + 4] = fmaf(wv, tm4, o2[w * 5 + 4]);
      }
    }
    __builtin_amdgcn_sched_barrier(0);

    // --- group D: xs[28:48) -> P13, P16, P17 ---
    float gd[20];
#pragma unroll
    for (int q = 0; q < 5; ++q) ((float4*)gd)[q] = xr[7 + q];
    // P13 (l2 x Y0 -> l2), wa=278
#pragma unroll
    for (int u = 0; u < 4; ++u) {
      float tm[5];
#pragma unroll
      for (int k = 0; k < 5; ++k) tm[k] = PS13 * gd[u * 5 + k];
#pragma unroll
      for (int w = 0; w < 4; ++w) {
        float wv = wdoth(sW, hid2, 278 + u * 4 + w);
#pragma unroll
        for (int k = 0; k < 5; ++k) o2[w * 5 + k] = fmaf(wv, tm[k], o2[w * 5 + k]);
      }
    }
    // P16 (l2 x Y2 -> l1e), C221 (antisym), wa=346
#pragma unroll
    for (int u = 0; u < 4; ++u) {
      float Xa0 = gd[u * 5 + 0], Xa1 = gd[u * 5 + 1], Xa2 = gd[u * 5 + 2];
      float Xa3 = gd[u * 5 + 3], Xa4 = gd[u * 5 + 4];
      float t0 = PS16 * (G122f * (Xa1 * Z2[4] - Xa4 * Z2[1]) + H122f * (Xa1 * Z2[2] - Xa2 * Z2[1]));
      float t1 = PS16 * (G122f * (-Xa0 * Z2[1] + Xa3 * Z2[4]) - H122f * Xa3 * Z2[2]);
      float t2 = PS16 * (G122f * Xa3 * Z2[1] - F122f * Xa0 * Z2[4]);
#pragma unroll
      for (int w = 0; w < 3; ++w) {
        float wv = wdoth(sW, hid2, 346 + u * 3 + w);
        oe[w * 3 + 0] = fmaf(wv, t0, oe[w * 3 + 0]);
        oe[w * 3 + 1] = fmaf(wv, t1, oe[w * 3 + 1]);
        oe[w * 3 + 2] = fmaf(wv, t2, oe[w * 3 + 2]);
      }
    }
    // P17 (l2 x Y2 -> l2), C222 (Gaunt), wa=358
#pragma unroll
    for (int u = 0; u < 4; ++u) {
      float Xa0 = gd[u * 5 + 0], Xa1 = gd[u * 5 + 1], Xa2 = gd[u * 5 + 2];
      float Xa3 = gd[u * 5 + 3], Xa4 = gd[u * 5 + 4];
      float tm[5];
      tm[0] = PS17 * (-2.f * P222f * Xa0 * Z2[2] + SP222f * Xa3 * Z2[1]);
      tm[1] = PS17 * (P222f * (Xa1 * Z2[2] + Xa2 * Z2[1]) + SP222f * (-Xa1 * Z2[4] - Xa4 * Z2[1]));
      tm[2] = PS17 * (P222f * Xa1 * Z2[1] + 2.f * P222f * (Xa2 * Z2[2] - Xa4 * Z2[4]));
      tm[3] = PS17 * (P222f * Xa3 * Z2[2] + SP222f * (Xa3 * Z2[4] + Xa0 * Z2[1]));
      tm[4] = PS17 * (SP222f * (-Xa1 * Z2[1]) - 2.f * P222f * (Xa2 * Z2[4] + Xa4 * Z2[2]));
#pragma unroll
      for (int w = 0; w < 4; ++w) {
        float wv = wdoth(sW, hid2, 358 + u * 4 + w);
#pragma unroll
        for (int k = 0; k < 5; ++k) o2[w * 5 + k] = fmaf(wv, tm[k], o2[w * 5 + k]);
      }
    }

    // store o[19:48]
    mp[19] = oe[0];
    float pk[28];
#pragma unroll
    for (int j = 0; j < 8; ++j) pk[j] = oe[1 + j];
#pragma unroll
    for (int j = 0; j < 20; ++j) pk[8 + j] = o2[j];
#pragma unroll
    for (int q = 0; q < 7; ++q) ((float4*)(mp + 20))[q] = ((float4*)pk)[q];
  }
}

// =================== CSR gather: one wave per node, lane = feature; contiguous rows ===================
__global__ void k_agg(const int* __restrict__ off, const float* __restrict__ MSG,
                      float* __restrict__ AGG) {
  int gt = blockIdx.x * blockDim.x + threadIdx.x;
  int wid = gt >> 6;          // node
  int lane = threadIdx.x & 63;
  if (wid >= BN) return;
  int a = off[wid], bnd = off[wid + 1];
  if (lane < 48) {
    float s = 0.f;
    for (int k = a; k < bnd; ++k) s += MSG[(size_t)k * 48 + lane];
    AGG[(size_t)wid * 48 + lane] = s;
  }
}

// =================== self-term + norm_act ===================
__global__ void k_post(const float* __restrict__ AGG, const float* __restrict__ hin,
                       const float* __restrict__ w0, const float* __restrict__ b0,
                       const float* __restrict__ w1o, const float* __restrict__ w1e,
                       const float* __restrict__ w2e, const float* __restrict__ mask_n,
                       float* __restrict__ hout) {
  int t = blockIdx.x * blockDim.x + threadIdx.x;
  if (t >= BN) return;
  float h[48], li[48], s[48];
  const float4* hp = (const float4*)(hin + (size_t)t * 48);
#pragma unroll
  for (int q = 0; q < 12; ++q) ((float4*)h)[q] = hp[q];
  lin48(h, w0, b0, w1o, w1e, w2e, li);
  const float4* gp = (const float4*)(AGG + (size_t)t * 48);
#pragma unroll
  for (int q = 0; q < 12; ++q) ((float4*)s)[q] = gp[q];
#pragma unroll
  for (int j = 0; j < 48; ++j) s[j] += li[j];
  float mk = mask_n[t];
  float r[48];
#pragma unroll
  for (int j = 0; j < 10; ++j) {
    float v = s[j];
    r[j] = v * sigm(sqrtf(v * v + 1e-12f)) * mk;
  }
#pragma unroll
  for (int u = 0; u < 3; ++u) {
    float n1 = 0.f, n2 = 0.f;
#pragma unroll
    for (int m = 0; m < 3; ++m) {
      n1 = fmaf(s[10 + u * 3 + m], s[10 + u * 3 + m], n1);
      n2 = fmaf(s[19 + u * 3 + m], s[19 + u * 3 + m], n2);
    }
    float f1 = sigm(sqrtf(n1 + 1e-12f)) * mk;
    float f2 = sigm(sqrtf(n2 + 1e-12f)) * mk;
#pragma unroll
    for (int m = 0; m < 3; ++m) {
      r[10 + u * 3 + m] = s[10 + u * 3 + m] * f1;
      r[19 + u * 3 + m] = s[19 + u * 3 + m] * f2;
    }
  }
#pragma unroll
  for (int u = 0; u < 4; ++u) {
    float n3 = 0.f;
#pragma unroll
    for (int m = 0; m < 5; ++m) n3 = fmaf(s[28 + u * 5 + m], s[28 + u * 5 + m], n3);
    float f3 = sigm(sqrtf(n3 + 1e-12f)) * mk;
#pragma unroll
    for (int m = 0; m < 5; ++m) r[28 + u * 5 + m] = s[28 + u * 5 + m] * f3;
  }
  float4* op = (float4*)(hout + (size_t)t * 48);
#pragma unroll
  for (int q = 0; q < 12; ++q) op[q] = ((float4*)r)[q];
}

// =================== readout ===================
__global__ void k_out(const float* __restrict__ h, const int* __restrict__ centers,
                      const float* __restrict__ sw0, const float* __restrict__ sb0,
                      const float* __restrict__ sw2, float* __restrict__ out) {
  int b = threadIdx.x;
  if (b >= Bb) return;
  int c = centers[b];
  const float* hc = h + ((size_t)(b * Nn + c)) * 48;
  float acc = 0.f;
#pragma unroll
  for (int u = 0; u < 10; ++u) acc = fmaf(hc[u], sw0[u], acc);
  float tr = acc * RS10f + sb0[0];
  float s2[5];
#pragma unroll
  for (int m = 0; m < 5; ++m) {
    float a = 0.f;
#pragma unroll
    for (int u = 0; u < 4; ++u) a = fmaf(hc[28 + u * 5 + m], sw2[u], a);
    s2[m] = a * 0.5f;
  }
  float a0 = s2[0], a2c = s2[1], a2s = s2[2], a1c = s2[3], a1s = s2[4];
  const float is6 = 0.4082482904638630f;
  const float is2 = 0.7071067811865476f;
  const float i3 = 0.3333333333333333f;
  out[b * 6 + 0] = -a0 * is6 + a2c * is2 + tr * i3;
  out[b * 6 + 1] = a2s;
  out[b * 6 + 2] = a1c;
  out[b * 6 + 3] = -a0 * is6 - a2c * is2 + tr * i3;
  out[b * 6 + 4] = a1s;
  out[b * 6 + 5] = 2.f * a0 * is6 + tr * i3;
}

// =================== host launch ===================
extern "C" void kernel_launch(void* const* d_in, const int* in_sizes, int n_in,
                              void* d_out, int out_size, void* d_ws, size_t ws_size,
                              hipStream_t stream) {
  const float* x_nodes = (const float*)d_in[0];
  const float* e_attr2 = (const float*)d_in[1];
  const float* mask_n  = (const float*)d_in[2];
  const float* mask_e  = (const float*)d_in[3];
  const float* enc_w0  = (const float*)d_in[4];
  const float* enc_b0  = (const float*)d_in[5];
  const float* enc_w1e = (const float*)d_in[6];
  const float* enc_w2e = (const float*)d_in[7];
  const float* li_w0   = (const float*)d_in[8];
  const float* li_b0   = (const float*)d_in[9];
  const float* li_w1o  = (const float*)d_in[10];
  const float* li_w1e  = (const float*)d_in[11];
  const float* li_w2e  = (const float*)d_in[12];
  const float* rad_w1  = (const float*)d_in[13];
  const float* rad_w2  = (const float*)d_in[14];
  const float* lr_w0   = (const float*)d_in[15];
  const float* lr_b0   = (const float*)d_in[16];
  const float* lr_w1o  = (const float*)d_in[17];
  const float* lr_w1e  = (const float*)d_in[18];
  const float* lr_w2e  = (const float*)d_in[19];
  const float* sym_w0  = (const float*)d_in[20];
  const float* sym_b0  = (const float*)d_in[21];
  const float* sym_w2e = (const float*)d_in[22];
  const int* e_src = (const int*)d_in[23];
  const int* e_dst = (const int*)d_in[24];
  const int* centers = (const int*)d_in[25];
  float* out = (float*)d_out;

  float* ws  = (float*)d_ws;
  float* hA  = ws;
  float* hB  = hA + (size_t)BN * 48;
  float* HIN = hB + (size_t)BN * 48;
  float* AGG = HIN + (size_t)BN * 48;
  float* MSG = AGG + (size_t)BN * 48;                 // BE*48 f32 = 50.3 MB
  uint32_t* R2T16 = (uint32_t*)(MSG + (size_t)BE * 48);
  int* deg    = (int*)(R2T16 + 2 * NW * 16);
  int* off    = deg + BN;        // BN+1
  int* cursor = off + BN + 1;
  int* bsum   = cursor + BN;     // 128
  int* boff   = bsum + 128;      // 128
  int* epos   = boff + 128;      // BE

  k_tr<<<3, 256, 0, stream>>>(rad_w2, R2T16);
  k_enc<<<BN / 256, 256, 0, stream>>>(x_nodes, mask_n, enc_w0, enc_b0, enc_w1e, enc_w2e, hA);

  // CSR of e_dst (constant across layers)
  (void)hipMemsetAsync(deg, 0, (size_t)BN * sizeof(int), stream);
  k_count<<<BE / 256, 256, 0, stream>>>(e_dst, deg);
  k_scan_block<<<BN / 256, 256, 0, stream>>>(deg, off, bsum);
  k_scan_bsum<<<1, 128, 0, stream>>>(bsum, boff);
  k_scan_add<<<BN / 256, 256, 0, stream>>>(boff, off, cursor);
  k_fill<<<BE / 256, 256, 0, stream>>>(e_dst, cursor, epos);

  float* hcur = hA;
  float* hnext = hB;
  for (int l = 0; l < 2; ++l) {
    k_lin<<<BN / 256, 256, 0, stream>>>(hcur, li_w0 + l * 100, li_b0 + l * 10,
                                        li_w1o + l * 9, li_w1e + l * 9, li_w2e + l * 16, HIN);
    k_msg<<<BE / 256, 256, 0, stream>>>(HIN, e_attr2, mask_e, rad_w1 + l * 32,
                                        R2T16 + (size_t)l * NW * 16, e_src, epos, MSG);
    k_agg<<<(BN * 64) / 256, 256, 0, stream>>>(off, MSG, AGG);
    k_post<<<BN / 256, 256, 0, stream>>>(AGG, hcur, lr_w0 + l * 100, lr_b0 + l * 10,
                                         lr_w1o + l * 9, lr_w1e + l * 9, lr_w2e + l * 16,
                                         mask_n, hnext);
    float* tswap = hcur; hcur = hnext; hnext = tswap;
  }
  k_out<<<1, 64, 0, stream>>>(hcur, centers, sym_w0, sym_b0, sym_w2e, out);
}